// Round 7
// baseline (671.001 us; speedup 1.0000x reference)
//
#include <hip/hip_runtime.h>
#include <hip/hip_fp16.h>
#include <math.h>

#define N_NODES_C  500000
#define N_EDGES_C  8000000
#define N_GRAPHS_C 1000
#define NGROUPS_C  (N_EDGES_C / 4)     // 2,000,000 float4-groups

// ---- workspace layout (32-bit word offsets) ----
#define GRAPH_ACC_OFF 0                          // 11000 floats
#define PARTIALS_OFF  11008                      // 2*11000 floats (zeroed; k_final adds)
#define FW_OFF        33024                      // 207 floats fused weights
#define NODE_ACC_OFF  33536                      // 500000 floats
#define ZERO_WORDS    (NODE_ACC_OFF + N_NODES_C) // 533,536 words (~2.1MB)

#define LOG2E_F 1.4426950408889634f

typedef int   int4v __attribute__((ext_vector_type(4)));
typedef float flt4v __attribute__((ext_vector_type(4)));

// fused-weight layout inside fw[]; (L) = pre-scaled by log2(e):
// 0:w_pn1[20](L) 20:b_pn1[10](L) 30:W_eb[50](L) 80:b_eb[5](L) 85:w1r0_e[5](L)
// 90:w2_e[5] 95:b2_e
// 96:w_pe1[5](L) 101:b_pe1[5](L) 106:pe_w2[50] 156:pe_b2[10]
// 166:W_nb[25](L) 191:b_nb[5](L) 196:w1r0_n[5](L) 201:w2_n[5] 206:b2_n

__device__ __forceinline__ float selu2(float xl) {
    const float C1 = 0.7282901039f;        // 1.0507009873554805 * ln(2)
    const float C2 = 1.7580993408473766f;  // scale * alpha
    float e = __builtin_amdgcn_exp2f(xl);
    float neg = fmaf(C2, e, -C2);
    return xl > 0.0f ? C1 * xl : neg;
}

__device__ __forceinline__ float selu_f(float x) {
    const float scale = 1.0507009873554805f;
    const float sa    = 1.0507009873554805f * 1.6732632423543772f;
    float neg = sa * (__expf(x) - 1.0f);
    return x > 0.0f ? scale * x : neg;
}

__device__ __forceinline__ void atomAddF(float* p, float v) {
    __hip_atomic_fetch_add(p, v, __ATOMIC_RELAXED, __HIP_MEMORY_SCOPE_AGENT);
}

__device__ __forceinline__ void fuse_weights(
        int t,
        const float* __restrict__ pn_w1, const float* __restrict__ pn_b1,
        const float* __restrict__ pn_w2, const float* __restrict__ pn_b2,
        const float* __restrict__ ue_w1, const float* __restrict__ ue_b1,
        const float* __restrict__ ue_w2, const float* __restrict__ ue_b2,
        const float* __restrict__ pe_w1, const float* __restrict__ pe_b1,
        const float* __restrict__ pe_w2, const float* __restrict__ pe_b2,
        const float* __restrict__ un_w1, const float* __restrict__ un_b1,
        const float* __restrict__ un_w2, const float* __restrict__ un_b2,
        float* __restrict__ fw) {
    const float L = LOG2E_F;
    if (t < 20) fw[0 + t] = pn_w1[t] * L;
    if (t < 10) fw[20 + t] = pn_b1[t] * L;
    if (t < 50) {
        int j = t / 5, k = t % 5;
        float s = 0.0f;
        for (int m = 0; m < 10; ++m) s += pn_w2[j * 10 + m] * ue_w1[(1 + m) * 5 + k];
        fw[30 + t] = s * L;
    }
    if (t < 5) {
        float s = ue_b1[t];
        for (int m = 0; m < 10; ++m) s += pn_b2[m] * ue_w1[(1 + m) * 5 + t];
        fw[80 + t] = s * L;
    }
    if (t < 5)  fw[85 + t]  = ue_w1[t] * L;
    if (t < 5)  fw[90 + t]  = ue_w2[t];
    if (t == 0) fw[95]      = ue_b2[0];
    if (t < 5)  fw[96 + t]  = pe_w1[t] * L;
    if (t < 5)  fw[101 + t] = pe_b1[t] * L;
    if (t < 50) fw[106 + t] = pe_w2[t];
    if (t < 10) fw[156 + t] = pe_b2[t];
    if (t < 25) {
        int j = t / 5, k = t % 5;
        float s = 0.0f;
        for (int m = 0; m < 10; ++m) s += pe_w2[j * 10 + m] * un_w1[(1 + m) * 5 + k];
        fw[166 + t] = s * L;
    }
    if (t < 5) {
        float s = un_b1[t];
        for (int m = 0; m < 10; ++m) s += pe_b2[m] * un_w1[(1 + m) * 5 + t];
        fw[191 + t] = s * L;
    }
    if (t < 5)  fw[196 + t] = un_w1[t] * L;
    if (t < 5)  fw[201 + t] = un_w2[t];
    if (t == 0) fw[206]     = un_b2[0];
}

__global__ __launch_bounds__(256) void k_zero(float* __restrict__ ws, int len4) {
    int i = blockIdx.x * 256 + threadIdx.x;
    if (i < len4) ((float4*)ws)[i] = make_float4(0.f, 0.f, 0.f, 0.f);
}

__global__ void k_fuse(const float* pn_w1, const float* pn_b1, const float* pn_w2, const float* pn_b2,
                       const float* ue_w1, const float* ue_b1, const float* ue_w2, const float* ue_b2,
                       const float* pe_w1, const float* pe_b1, const float* pe_w2, const float* pe_b2,
                       const float* un_w1, const float* un_b1, const float* un_w2, const float* un_b2,
                       float* fw) {
    fuse_weights(threadIdx.x, pn_w1, pn_b1, pn_w2, pn_b2, ue_w1, ue_b1, ue_w2, ue_b2,
                 pe_w1, pe_b1, pe_w2, pe_b2, un_w1, un_b1, un_w2, un_b2, fw);
}

// k_edges: edge MLP + global atomicAdd scatter to node_acc[recv].
// No LDS, no sort, no intermediate: read e/s/r as nontemporal streams
// (keeps L2 dedicated to the 2MB nodes + 2MB node_acc arrays, so the
// 16M random gathers and 8M atomics are L2-resident). Occupancy limited
// only by VGPRs.
__global__ __launch_bounds__(256) void k_edges(
        const float* __restrict__ nodes, const float* __restrict__ edges,
        const int* __restrict__ senders, const int* __restrict__ receivers,
        const float* __restrict__ fw, float* __restrict__ node_acc) {
    float w_pn1[20], b_pn1[10], W_eb[50], b_eb[5], w1r0[5], w2e[5];
#pragma unroll
    for (int j = 0; j < 20; ++j) w_pn1[j] = fw[j];
#pragma unroll
    for (int j = 0; j < 10; ++j) b_pn1[j] = fw[20 + j];
#pragma unroll
    for (int j = 0; j < 50; ++j) W_eb[j] = fw[30 + j];
#pragma unroll
    for (int j = 0; j < 5; ++j) b_eb[j] = fw[80 + j];
#pragma unroll
    for (int j = 0; j < 5; ++j) w1r0[j] = fw[85 + j];
#pragma unroll
    for (int j = 0; j < 5; ++j) w2e[j] = fw[90 + j];
    float b2e = fw[95];

    int g = blockIdx.x * 256 + threadIdx.x;
    if (g >= NGROUPS_C) return;

    flt4v e4 = __builtin_nontemporal_load((const flt4v*)edges + g);
    int4v s4 = __builtin_nontemporal_load((const int4v*)senders + g);
    int4v r4 = __builtin_nontemporal_load((const int4v*)receivers + g);
    float ev[4] = {e4[0], e4[1], e4[2], e4[3]};
    int   sv[4] = {s4[0], s4[1], s4[2], s4[3]};
    int   rv[4] = {r4[0], r4[1], r4[2], r4[3]};
    // all 8 gathers issued back-to-back (independent; L2-resident)
    float nsv[4], nrv[4];
#pragma unroll
    for (int u = 0; u < 4; ++u) { nsv[u] = nodes[sv[u]]; nrv[u] = nodes[rv[u]]; }
#pragma unroll
    for (int u = 0; u < 4; ++u) {
        float nr = nrv[u], ns = nsv[u];
        float bs[5];
#pragma unroll
        for (int k = 0; k < 5; ++k) bs[k] = b_eb[k];
#pragma unroll
        for (int j = 0; j < 10; ++j) {
            float zl = fmaf(nr, w_pn1[j], fmaf(ns, w_pn1[10 + j], b_pn1[j]));
            float sz = selu2(zl);
#pragma unroll
            for (int k = 0; k < 5; ++k) bs[k] = fmaf(sz, W_eb[j * 5 + k], bs[k]);
        }
        float e = ev[u];
#pragma unroll
        for (int it = 0; it < 3; ++it) {
            float acc2 = b2e;
#pragma unroll
            for (int k = 0; k < 5; ++k) {
                float tt = selu2(fmaf(e, w1r0[k], bs[k]));
                acc2 = fmaf(tt, w2e[k], acc2);
            }
            e = acc2;
        }
        atomAddF(&node_acc[rv[u]], e);
    }
}

// k_nodes: node MLP + graph reduction (proven epilogue).
__global__ __launch_bounds__(256) void k_nodes(
        const float* __restrict__ nodes, const int* __restrict__ graph_ids,
        const float* __restrict__ fw, const float* __restrict__ node_acc,
        float* __restrict__ graph_acc) {
    float w_pe1[5], b_pe1[5], pe_w2[50], pe_b2[10], W_nb[25], b_nb[5], w1r0n[5], w2n[5];
#pragma unroll
    for (int j = 0; j < 5; ++j) w_pe1[j] = fw[96 + j];
#pragma unroll
    for (int j = 0; j < 5; ++j) b_pe1[j] = fw[101 + j];
#pragma unroll
    for (int j = 0; j < 50; ++j) pe_w2[j] = fw[106 + j];
#pragma unroll
    for (int j = 0; j < 10; ++j) pe_b2[j] = fw[156 + j];
#pragma unroll
    for (int j = 0; j < 25; ++j) W_nb[j] = fw[166 + j];
#pragma unroll
    for (int j = 0; j < 5; ++j) b_nb[j] = fw[191 + j];
#pragma unroll
    for (int j = 0; j < 5; ++j) w1r0n[j] = fw[196 + j];
#pragma unroll
    for (int j = 0; j < 5; ++j) w2n[j] = fw[201 + j];
    float b2n = fw[206];

    int i = blockIdx.x * 256 + threadIdx.x;
    bool valid = i < N_NODES_C;
    int ii = valid ? i : (N_NODES_C - 1);

    float s = node_acc[ii];
    float t5[5];
#pragma unroll
    for (int k = 0; k < 5; ++k) t5[k] = selu2(fmaf(s, w_pe1[k], b_pe1[k]));
    float he[10];
#pragma unroll
    for (int m = 0; m < 10; ++m) {
        float a = pe_b2[m];
#pragma unroll
        for (int k = 0; k < 5; ++k) a = fmaf(t5[k], pe_w2[k * 10 + m], a);
        he[m] = a;
    }
    float bs[5];
#pragma unroll
    for (int k = 0; k < 5; ++k) {
        float a = b_nb[k];
#pragma unroll
        for (int t = 0; t < 5; ++t) a = fmaf(t5[t], W_nb[t * 5 + k], a);
        bs[k] = a;
    }
    float n = nodes[ii];
#pragma unroll
    for (int it = 0; it < 3; ++it) {
        float a = b2n;
#pragma unroll
        for (int k = 0; k < 5; ++k) {
            float tt = selu2(fmaf(n, w1r0n[k], bs[k]));
            a = fmaf(tt, w2n[k], a);
        }
        n = a;
    }

    int gid = valid ? graph_ids[ii] : -1;
    if (!valid) {
        n = 0.0f;
#pragma unroll
        for (int m = 0; m < 10; ++m) he[m] = 0.0f;
    }

    int gid0 = __shfl(gid, 0, 64);
    bool allsame = __all(gid == gid0) && (gid0 >= 0);
    if (allsame) {
        float v = n;
#pragma unroll
        for (int off = 32; off > 0; off >>= 1) v += __shfl_down(v, off, 64);
        float vh[10];
#pragma unroll
        for (int m = 0; m < 10; ++m) {
            float ww = he[m];
#pragma unroll
            for (int off = 32; off > 0; off >>= 1) ww += __shfl_down(ww, off, 64);
            vh[m] = ww;
        }
        if ((threadIdx.x & 63) == 0) {
            atomAddF(&graph_acc[gid0 * 11 + 0], v);
#pragma unroll
            for (int m = 0; m < 10; ++m) atomAddF(&graph_acc[gid0 * 11 + 1 + m], vh[m]);
        }
    } else if (valid) {
        atomAddF(&graph_acc[gid * 11 + 0], n);
#pragma unroll
        for (int m = 0; m < 10; ++m) atomAddF(&graph_acc[gid * 11 + 1 + m], he[m]);
    }
}

__global__ void k_final(const float* __restrict__ graph_acc,
                        const float* __restrict__ partials,
                        const float* __restrict__ pr_w1, const float* __restrict__ pr_b1,
                        const float* __restrict__ pr_w2, const float* __restrict__ pr_b2,
                        float* __restrict__ out) {
    int g = blockIdx.x * blockDim.x + threadIdx.x;
    if (g >= N_GRAPHS_C) return;
    float gv[11];
#pragma unroll
    for (int f = 0; f < 11; ++f)
        gv[f] = graph_acc[g * 11 + f] + partials[g * 11 + f] + partials[11000 + g * 11 + f];
    float h[10];
#pragma unroll
    for (int j = 0; j < 10; ++j) {
        float z = pr_b1[j];
#pragma unroll
        for (int f = 0; f < 11; ++f) z = fmaf(gv[f], pr_w1[f * 10 + j], z);
        h[j] = selu_f(z);
    }
    float o[10];
    float mx = -1e30f;
#pragma unroll
    for (int j = 0; j < 10; ++j) {
        float z = pr_b2[j];
#pragma unroll
        for (int m = 0; m < 10; ++m) z = fmaf(h[m], pr_w2[m * 10 + j], z);
        o[j] = z;
        mx = fmaxf(mx, z);
    }
    float sum = 0.0f;
#pragma unroll
    for (int j = 0; j < 10; ++j) { o[j] = __expf(o[j] - mx); sum += o[j]; }
    float inv = 1.0f / sum;
#pragma unroll
    for (int j = 0; j < 10; ++j) out[g * 10 + j] = o[j] * inv;
}

// ---------------- launch ----------------

extern "C" void kernel_launch(void* const* d_in, const int* in_sizes, int n_in,
                              void* d_out, int out_size, void* d_ws, size_t ws_size,
                              hipStream_t stream) {
    const float* nodes     = (const float*)d_in[0];
    const float* edges     = (const float*)d_in[1];
    const int*   senders   = (const int*)d_in[2];
    const int*   receivers = (const int*)d_in[3];
    const int*   graph_ids = (const int*)d_in[4];
    const float* pn_w1 = (const float*)d_in[6];
    const float* pn_b1 = (const float*)d_in[7];
    const float* pn_w2 = (const float*)d_in[8];
    const float* pn_b2 = (const float*)d_in[9];
    const float* ue_w1 = (const float*)d_in[10];
    const float* ue_b1 = (const float*)d_in[11];
    const float* ue_w2 = (const float*)d_in[12];
    const float* ue_b2 = (const float*)d_in[13];
    const float* pe_w1 = (const float*)d_in[14];
    const float* pe_b1 = (const float*)d_in[15];
    const float* pe_w2 = (const float*)d_in[16];
    const float* pe_b2 = (const float*)d_in[17];
    const float* un_w1 = (const float*)d_in[18];
    const float* un_b1 = (const float*)d_in[19];
    const float* un_w2 = (const float*)d_in[20];
    const float* un_b2 = (const float*)d_in[21];
    const float* pr_w1 = (const float*)d_in[22];
    const float* pr_b1 = (const float*)d_in[23];
    const float* pr_w2 = (const float*)d_in[24];
    const float* pr_b2 = (const float*)d_in[25];

    float* ws        = (float*)d_ws;
    float* graph_acc = ws + GRAPH_ACC_OFF;
    float* partials  = ws + PARTIALS_OFF;
    float* fw        = ws + FW_OFF;
    float* node_acc  = ws + NODE_ACC_OFF;
    float* outp      = (float*)d_out;

    // atomic-scatter path: zero accumulators -> fuse weights ->
    // edge MLP + atomic scatter -> node MLP + graph reduce -> predict
    int len4 = ZERO_WORDS / 4;
    hipLaunchKernelGGL(k_zero, dim3((len4 + 255) / 256), dim3(256), 0, stream, ws, len4);
    hipLaunchKernelGGL(k_fuse, dim3(1), dim3(64), 0, stream,
                       pn_w1, pn_b1, pn_w2, pn_b2, ue_w1, ue_b1, ue_w2, ue_b2,
                       pe_w1, pe_b1, pe_w2, pe_b2, un_w1, un_b1, un_w2, un_b2, fw);
    hipLaunchKernelGGL(k_edges, dim3((NGROUPS_C + 255) / 256), dim3(256), 0, stream,
                       nodes, edges, senders, receivers, fw, node_acc);
    hipLaunchKernelGGL(k_nodes, dim3((N_NODES_C + 255) / 256), dim3(256), 0, stream,
                       nodes, graph_ids, fw, node_acc, graph_acc);
    hipLaunchKernelGGL(k_final, dim3((N_GRAPHS_C + 255) / 256), dim3(256), 0, stream,
                       graph_acc, partials, pr_w1, pr_b1, pr_w2, pr_b2, outp);
}

// Round 8
// 300.360 us; speedup vs baseline: 2.2340x; 2.2340x over previous
//
#include <hip/hip_runtime.h>
#include <hip/hip_fp16.h>
#include <math.h>

#define N_NODES_C  500000
#define N_EDGES_C  8000000
#define N_GRAPHS_C 1000
#define NGROUPS_C  (N_EDGES_C / 4)     // 2,000,000 float4-groups

#define BSHIFT  11                     // bucket = recv >> 11
#define BWIDTH  2048
#define NBKT    245                    // ceil(500000 / 2048)

#define P2_TPB  512
#define EPB2    8192                   // edges per part-block (64KB staged u64)
#define GPB2    (EPB2 / 4)             // 2048 groups
#define NPB2    ((NGROUPS_C + GPB2 - 1) / GPB2) // 977
#define SROW2   992
#define RITER2  (GPB2 / P2_TPB)        // 4

// ---- workspace layout (32-bit word offsets) ----
#define GRAPH_ACC_OFF 0                          // 11000 floats
#define PARTIALS_OFF  11008                      // 2*11000 floats
#define FW_OFF        33024                      // 207 floats fused weights
#define ZERO_HEAD     33024                      // graph_acc + partials

#define STARTS2_OFF   33280                      // 246 * SROW2 ints
#define PAIRS64_OFF   (STARTS2_OFF + 246 * SROW2)        // 277312; *4%16==0
#define WS2_WORDS_NEEDED (PAIRS64_OFF + NPB2 * EPB2 * 2) // 16,284,480 (65.1MB)

// fallback layout
#define OLD_NODE_ACC_OFF 33536
#define OLD_ZERO_WORDS   (OLD_NODE_ACC_OFF + N_NODES_C)

#define LOG2E_F 1.4426950408889634f

// fused-weight layout inside fw[]; (L) = pre-scaled by log2(e):
// 0:w_pn1[20](L) 20:b_pn1[10](L) 30:W_eb[50](L) 80:b_eb[5](L) 85:w1r0_e[5](L)
// 90:w2_e[5] 95:b2_e
// 96:w_pe1[5](L) 101:b_pe1[5](L) 106:pe_w2[50] 156:pe_b2[10]
// 166:W_nb[25](L) 191:b_nb[5](L) 196:w1r0_n[5](L) 201:w2_n[5] 206:b2_n

__device__ __forceinline__ float selu2(float xl) {
    const float C1 = 0.7282901039f;        // 1.0507009873554805 * ln(2)
    const float C2 = 1.7580993408473766f;  // scale * alpha
    float e = __builtin_amdgcn_exp2f(xl);
    float neg = fmaf(C2, e, -C2);
    return xl > 0.0f ? C1 * xl : neg;
}

__device__ __forceinline__ float selu_f(float x) {
    const float scale = 1.0507009873554805f;
    const float sa    = 1.0507009873554805f * 1.6732632423543772f;
    float neg = sa * (__expf(x) - 1.0f);
    return x > 0.0f ? scale * x : neg;
}

__device__ __forceinline__ void atomAddF(float* p, float v) {
    __hip_atomic_fetch_add(p, v, __ATOMIC_RELAXED, __HIP_MEMORY_SCOPE_AGENT);
}

__device__ __forceinline__ void fuse_weights(
        int t,
        const float* __restrict__ pn_w1, const float* __restrict__ pn_b1,
        const float* __restrict__ pn_w2, const float* __restrict__ pn_b2,
        const float* __restrict__ ue_w1, const float* __restrict__ ue_b1,
        const float* __restrict__ ue_w2, const float* __restrict__ ue_b2,
        const float* __restrict__ pe_w1, const float* __restrict__ pe_b1,
        const float* __restrict__ pe_w2, const float* __restrict__ pe_b2,
        const float* __restrict__ un_w1, const float* __restrict__ un_b1,
        const float* __restrict__ un_w2, const float* __restrict__ un_b2,
        float* __restrict__ fw) {
    const float L = LOG2E_F;
    if (t < 20) fw[0 + t] = pn_w1[t] * L;
    if (t < 10) fw[20 + t] = pn_b1[t] * L;
    if (t < 50) {
        int j = t / 5, k = t % 5;
        float s = 0.0f;
        for (int m = 0; m < 10; ++m) s += pn_w2[j * 10 + m] * ue_w1[(1 + m) * 5 + k];
        fw[30 + t] = s * L;
    }
    if (t < 5) {
        float s = ue_b1[t];
        for (int m = 0; m < 10; ++m) s += pn_b2[m] * ue_w1[(1 + m) * 5 + t];
        fw[80 + t] = s * L;
    }
    if (t < 5)  fw[85 + t]  = ue_w1[t] * L;
    if (t < 5)  fw[90 + t]  = ue_w2[t];
    if (t == 0) fw[95]      = ue_b2[0];
    if (t < 5)  fw[96 + t]  = pe_w1[t] * L;
    if (t < 5)  fw[101 + t] = pe_b1[t] * L;
    if (t < 50) fw[106 + t] = pe_w2[t];
    if (t < 10) fw[156 + t] = pe_b2[t];
    if (t < 25) {
        int j = t / 5, k = t % 5;
        float s = 0.0f;
        for (int m = 0; m < 10; ++m) s += pe_w2[j * 10 + m] * un_w1[(1 + m) * 5 + k];
        fw[166 + t] = s * L;
    }
    if (t < 5) {
        float s = un_b1[t];
        for (int m = 0; m < 10; ++m) s += pe_b2[m] * un_w1[(1 + m) * 5 + t];
        fw[191 + t] = s * L;
    }
    if (t < 5)  fw[196 + t] = un_w1[t] * L;
    if (t < 5)  fw[201 + t] = un_w2[t];
    if (t == 0) fw[206]     = un_b2[0];
}

__global__ void k_fuse(const float* pn_w1, const float* pn_b1, const float* pn_w2, const float* pn_b2,
                       const float* ue_w1, const float* ue_b1, const float* ue_w2, const float* ue_b2,
                       const float* pe_w1, const float* pe_b1, const float* pe_w2, const float* pe_b2,
                       const float* un_w1, const float* un_b1, const float* un_w2, const float* un_b2,
                       float* fw) {
    fuse_weights(threadIdx.x, pn_w1, pn_b1, pn_w2, pn_b2, ue_w1, ue_b1, ue_w2, ue_b2,
                 pe_w1, pe_b1, pe_w2, pe_b2, un_w1, un_b1, un_w2, un_b2, fw);
}

__global__ void k_final(const float* __restrict__ graph_acc,
                        const float* __restrict__ partials,
                        const float* __restrict__ pr_w1, const float* __restrict__ pr_b1,
                        const float* __restrict__ pr_w2, const float* __restrict__ pr_b2,
                        float* __restrict__ out) {
    int g = blockIdx.x * blockDim.x + threadIdx.x;
    if (g >= N_GRAPHS_C) return;
    float gv[11];
#pragma unroll
    for (int f = 0; f < 11; ++f)
        gv[f] = graph_acc[g * 11 + f] + partials[g * 11 + f] + partials[11000 + g * 11 + f];
    float h[10];
#pragma unroll
    for (int j = 0; j < 10; ++j) {
        float z = pr_b1[j];
#pragma unroll
        for (int f = 0; f < 11; ++f) z = fmaf(gv[f], pr_w1[f * 10 + j], z);
        h[j] = selu_f(z);
    }
    float o[10];
    float mx = -1e30f;
#pragma unroll
    for (int j = 0; j < 10; ++j) {
        float z = pr_b2[j];
#pragma unroll
        for (int m = 0; m < 10; ++m) z = fmaf(h[m], pr_w2[m * 10 + j], z);
        o[j] = z;
        mx = fmaxf(mx, z);
    }
    float sum = 0.0f;
#pragma unroll
    for (int j = 0; j < 10; ++j) { o[j] = __expf(o[j] - mx); sum += o[j]; }
    float inv = 1.0f / sum;
#pragma unroll
    for (int j = 0; j < 10; ++j) out[g * 10 + j] = o[j] * inv;
}

// ==================== main path: sort-first, MLP-in-gather ====================
// (round-3 champion structure, 293us verified; init fused into part2,
//  batch-2 ILP added to gather2's edge loop)

// k_part2: streaming counting sort ONLY (no MLP, no node gathers).
// Packs u64 {recv_local:11 @bit51 | sender:19 @bit32 | edge f32 @bit0}.
// Fused init: each block zeros a 34-word slice of graph_acc/partials;
// block 0 additionally builds the fused weights (consumed only by the
// NEXT kernel, so no intra-kernel ordering needed).
__global__ __launch_bounds__(P2_TPB) void k_part2(
        float* __restrict__ ws,
        const float* __restrict__ edges,
        const int* __restrict__ senders, const int* __restrict__ receivers,
        int* __restrict__ starts_T, unsigned long long* __restrict__ pairs64,
        const float* pn_w1, const float* pn_b1, const float* pn_w2, const float* pn_b2,
        const float* ue_w1, const float* ue_b1, const float* ue_w2, const float* ue_b2,
        const float* pe_w1, const float* pe_b1, const float* pe_w2, const float* pe_b2,
        const float* un_w1, const float* un_b1, const float* un_w2, const float* un_b2) {
    __shared__ int hist[256];
    __shared__ int cursorS[256];
    __shared__ alignas(16) unsigned long long staged[EPB2];   // 64 KB

    int tid = threadIdx.x;
    int p   = blockIdx.x;

    // fused init
    if (tid < 34) {
        int z = p * 34 + tid;
        if (z < ZERO_HEAD) ws[z] = 0.0f;
    }
    if (p == 0)
        fuse_weights(tid, pn_w1, pn_b1, pn_w2, pn_b2, ue_w1, ue_b1, ue_w2, ue_b2,
                     pe_w1, pe_b1, pe_w2, pe_b2, un_w1, un_b1, un_w2, un_b2, ws + FW_OFF);

    int gstart = p * GPB2;
    int gnum   = NGROUPS_C - gstart;
    if (gnum > GPB2) gnum = GPB2;

    if (tid < 256) hist[tid] = 0;
    __syncthreads();

    // phase A: load receivers (kept in regs), histogram
    int4 rv4[RITER2];
#pragma unroll
    for (int r = 0; r < RITER2; ++r) {
        int idx = r * P2_TPB + tid;
        int gi  = gstart + (idx < gnum ? idx : 0);
        rv4[r] = ((const int4*)receivers)[gi];
        if (idx < gnum) {
            atomicAdd(&hist[rv4[r].x >> BSHIFT], 1);
            atomicAdd(&hist[rv4[r].y >> BSHIFT], 1);
            atomicAdd(&hist[rv4[r].z >> BSHIFT], 1);
            atomicAdd(&hist[rv4[r].w >> BSHIFT], 1);
        }
    }
    __syncthreads();

    // inclusive scan over 256 buckets (tids 0..255 active)
    int orig = 0, val = 0;
    if (tid < 256) { orig = hist[tid]; val = orig; }
    for (int d = 1; d < 256; d <<= 1) {
        int add = 0;
        if (tid >= d && tid < 256) add = hist[tid - d];
        __syncthreads();
        if (tid >= d && tid < 256) { val += add; hist[tid] = val; }
        __syncthreads();
    }
    int excl = val - orig;
    if (tid < 256) cursorS[tid] = excl;
    if (tid < 246) starts_T[tid * SROW2 + p] = excl;
    __syncthreads();

    // phase C: pack + counting sort into LDS
#pragma unroll
    for (int r = 0; r < RITER2; ++r) {
        int idx = r * P2_TPB + tid;
        int gi  = gstart + (idx < gnum ? idx : 0);
        float4 e4 = ((const float4*)edges)[gi];
        int4   s4 = ((const int4*)senders)[gi];
        int4   rv = rv4[r];
        if (idx < gnum) {
            int   rvv[4] = {rv.x, rv.y, rv.z, rv.w};
            int   svv[4] = {s4.x, s4.y, s4.z, s4.w};
            float evv[4] = {e4.x, e4.y, e4.z, e4.w};
#pragma unroll
            for (int u = 0; u < 4; ++u) {
                int bkt  = rvv[u] >> BSHIFT;
                int slot = atomicAdd(&cursorS[bkt], 1);
                unsigned long long pk =
                    ((unsigned long long)(rvv[u] & (BWIDTH - 1)) << 51)
                  | ((unsigned long long)(unsigned)svv[u] << 32)
                  | (unsigned long long)__float_as_uint(evv[u]);
                staged[slot] = pk;
            }
        }
    }
    __syncthreads();

    // flush: contiguous uint4 stores (gnum*4 u64 = gnum*2 uint4)
    const uint4* st4 = (const uint4*)staged;
    uint4* dst = (uint4*)(pairs64 + (size_t)p * EPB2);
    int n4 = gnum * 2;
    for (int i = tid; i < n4; i += P2_TPB) dst[i] = st4[i];
}

// k_gather2: per bucket — stage 2048 node feats in LDS (coalesced),
// prefix-sum worklist over the 977 segments; edge MLP runs BATCH-2 with
// interleaved independent binary searches (overlaps the two dependent
// LDS-chains + the two random sender loads). Then node MLP + graph
// reduction with parity-partials.
__global__ __launch_bounds__(1024) void k_gather2(
        const float* __restrict__ nodes, const int* __restrict__ graph_ids,
        const float* __restrict__ fw, const int* __restrict__ starts_T,
        const unsigned long long* __restrict__ pairs64,
        float* __restrict__ graph_acc, float* __restrict__ partials) {
    __shared__ float accf[BWIDTH];        // 8 KB
    __shared__ float nf[BWIDTH];          // 8 KB staged node feats
    __shared__ int   s0[NPB2];            // 3.9 KB
    __shared__ int   pst[NPB2 + 1];       // 3.9 KB prefix of segment counts
    __shared__ int   sc[1024];            // 4 KB scan scratch
    __shared__ float garr[32 * 11];
    int tid = threadIdx.x;
    int b   = blockIdx.x;

    int nodeBase = b << BSHIFT;
    int lastIdx  = nodeBase + BWIDTH;
    if (lastIdx > N_NODES_C) lastIdx = N_NODES_C;
    int lim = lastIdx - nodeBase;

    accf[tid] = 0.0f; accf[1024 + tid] = 0.0f;
    nf[tid]        = (tid        < lim) ? nodes[nodeBase + tid]        : 0.0f;
    nf[1024 + tid] = (1024 + tid < lim) ? nodes[nodeBase + 1024 + tid] : 0.0f;
    if (tid < 352) garr[tid] = 0.0f;

    int cntv = 0;
    if (tid < NPB2) {
        int a = starts_T[b * SROW2 + tid];
        int c = starts_T[(b + 1) * SROW2 + tid];
        s0[tid] = a;
        cntv = c - a;
    }
    sc[tid] = cntv;
    __syncthreads();

    // inclusive scan over 1024 (977 real + zero pad)
    int v = cntv;
    for (int d = 1; d < 1024; d <<= 1) {
        int add = (tid >= d) ? sc[tid - d] : 0;
        __syncthreads();
        if (tid >= d) { v += add; sc[tid] = v; }
        __syncthreads();
    }
    if (tid == 0) pst[0] = 0;
    if (tid < NPB2) pst[tid + 1] = v;
    __syncthreads();

    int M = pst[NPB2];   // total edges for this bucket

    // ---- edge MLP over the worklist (edge weights scoped here) ----
    {
        float w_pn1[20], b_pn1[10], W_eb[50], b_eb[5], w1r0[5], w2e[5];
#pragma unroll
        for (int j = 0; j < 20; ++j) w_pn1[j] = fw[j];
#pragma unroll
        for (int j = 0; j < 10; ++j) b_pn1[j] = fw[20 + j];
#pragma unroll
        for (int j = 0; j < 50; ++j) W_eb[j] = fw[30 + j];
#pragma unroll
        for (int j = 0; j < 5; ++j) b_eb[j] = fw[80 + j];
#pragma unroll
        for (int j = 0; j < 5; ++j) w1r0[j] = fw[85 + j];
#pragma unroll
        for (int j = 0; j < 5; ++j) w2e[j] = fw[90 + j];
        float b2e = fw[95];

        int i = tid;
#pragma unroll 1
        for (; i + 1024 < M; i += 2048) {
            int iA = i, iB = i + 1024;
            int loA = 0, hiA = NPB2, loB = 0, hiB = NPB2;
#pragma unroll
            for (int s = 0; s < 10; ++s) {   // ceil(log2(977)) = 10
                int mA = (loA + hiA) >> 1;
                int mB = (loB + hiB) >> 1;
                int pA = pst[mA];
                int pB = pst[mB];
                if (pA <= iA) loA = mA; else hiA = mA;
                if (pB <= iB) loB = mB; else hiB = mB;
            }
            unsigned long long pkA =
                pairs64[(size_t)loA * EPB2 + s0[loA] + (iA - pst[loA])];
            unsigned long long pkB =
                pairs64[(size_t)loB * EPB2 + s0[loB] + (iB - pst[loB])];
            float nsA = nodes[(int)((pkA >> 32) & 0x7FFFFULL)];
            float nsB = nodes[(int)((pkB >> 32) & 0x7FFFFULL)];
            int   rlA = (int)(pkA >> 51);
            int   rlB = (int)(pkB >> 51);
            float nrA = nf[rlA];
            float nrB = nf[rlB];
            float eA  = __uint_as_float((unsigned)pkA);
            float eB  = __uint_as_float((unsigned)pkB);

            float bsA[5], bsB[5];
#pragma unroll
            for (int k = 0; k < 5; ++k) { bsA[k] = b_eb[k]; bsB[k] = b_eb[k]; }
#pragma unroll
            for (int j = 0; j < 10; ++j) {
                float zlA = fmaf(nrA, w_pn1[j], fmaf(nsA, w_pn1[10 + j], b_pn1[j]));
                float zlB = fmaf(nrB, w_pn1[j], fmaf(nsB, w_pn1[10 + j], b_pn1[j]));
                float szA = selu2(zlA);
                float szB = selu2(zlB);
#pragma unroll
                for (int k = 0; k < 5; ++k) {
                    bsA[k] = fmaf(szA, W_eb[j * 5 + k], bsA[k]);
                    bsB[k] = fmaf(szB, W_eb[j * 5 + k], bsB[k]);
                }
            }
#pragma unroll
            for (int it = 0; it < 3; ++it) {
                float aA = b2e, aB = b2e;
#pragma unroll
                for (int k = 0; k < 5; ++k) {
                    float tA = selu2(fmaf(eA, w1r0[k], bsA[k]));
                    float tB = selu2(fmaf(eB, w1r0[k], bsB[k]));
                    aA = fmaf(tA, w2e[k], aA);
                    aB = fmaf(tB, w2e[k], aB);
                }
                eA = aA; eB = aB;
            }
            atomicAdd(&accf[rlA], eA);
            atomicAdd(&accf[rlB], eB);
        }
#pragma unroll 1
        for (; i < M; i += 1024) {
            int lo = 0, hi = NPB2;
#pragma unroll
            for (int s = 0; s < 10; ++s) {
                int mid = (lo + hi) >> 1;
                if (pst[mid] <= i) lo = mid; else hi = mid;
            }
            unsigned long long pk =
                pairs64[(size_t)lo * EPB2 + s0[lo] + (i - pst[lo])];
            int   rl   = (int)(pk >> 51);
            int   sidx = (int)((pk >> 32) & 0x7FFFFULL);
            float e    = __uint_as_float((unsigned)pk);
            float nr   = nf[rl];
            float ns   = nodes[sidx];

            float bs[5];
#pragma unroll
            for (int k = 0; k < 5; ++k) bs[k] = b_eb[k];
#pragma unroll
            for (int j = 0; j < 10; ++j) {
                float zl = fmaf(nr, w_pn1[j], fmaf(ns, w_pn1[10 + j], b_pn1[j]));
                float sz = selu2(zl);
#pragma unroll
                for (int k = 0; k < 5; ++k) bs[k] = fmaf(sz, W_eb[j * 5 + k], bs[k]);
            }
#pragma unroll
            for (int it = 0; it < 3; ++it) {
                float acc2 = b2e;
#pragma unroll
                for (int k = 0; k < 5; ++k) {
                    float tt = selu2(fmaf(e, w1r0[k], bs[k]));
                    acc2 = fmaf(tt, w2e[k], acc2);
                }
                e = acc2;
            }
            atomicAdd(&accf[rl], e);
        }
    }
    __syncthreads();

    // ---- node MLP + graph reduction (node weights scoped here) ----
    float w_pe1[5], b_pe1[5], pe_w2[50], pe_b2[10], W_nb[25], b_nb[5], w1r0n[5], w2n[5];
#pragma unroll
    for (int j = 0; j < 5; ++j) w_pe1[j] = fw[96 + j];
#pragma unroll
    for (int j = 0; j < 5; ++j) b_pe1[j] = fw[101 + j];
#pragma unroll
    for (int j = 0; j < 50; ++j) pe_w2[j] = fw[106 + j];
#pragma unroll
    for (int j = 0; j < 10; ++j) pe_b2[j] = fw[156 + j];
#pragma unroll
    for (int j = 0; j < 25; ++j) W_nb[j] = fw[166 + j];
#pragma unroll
    for (int j = 0; j < 5; ++j) b_nb[j] = fw[191 + j];
#pragma unroll
    for (int j = 0; j < 5; ++j) w1r0n[j] = fw[196 + j];
#pragma unroll
    for (int j = 0; j < 5; ++j) w2n[j] = fw[201 + j];
    float b2n = fw[206];

    int gidBase = graph_ids[nodeBase];
    int gidEnd  = graph_ids[lastIdx - 1];

#pragma unroll
    for (int q = 0; q < 2; ++q) {
        int local = q * 1024 + tid;
        int i = nodeBase + local;
        bool valid = i < N_NODES_C;

        float s = accf[local];
        float t5[5];
#pragma unroll
        for (int k = 0; k < 5; ++k) t5[k] = selu2(fmaf(s, w_pe1[k], b_pe1[k]));
        float he[10];
#pragma unroll
        for (int m = 0; m < 10; ++m) {
            float a = pe_b2[m];
#pragma unroll
            for (int k = 0; k < 5; ++k) a = fmaf(t5[k], pe_w2[k * 10 + m], a);
            he[m] = a;
        }
        float bs[5];
#pragma unroll
        for (int k = 0; k < 5; ++k) {
            float a = b_nb[k];
#pragma unroll
            for (int t = 0; t < 5; ++t) a = fmaf(t5[t], W_nb[t * 5 + k], a);
            bs[k] = a;
        }
        float n = valid ? nf[local] : 0.0f;
#pragma unroll
        for (int it = 0; it < 3; ++it) {
            float a = b2n;
#pragma unroll
            for (int k = 0; k < 5; ++k) {
                float tt = selu2(fmaf(n, w1r0n[k], bs[k]));
                a = fmaf(tt, w2n[k], a);
            }
            n = a;
        }

        int gid = valid ? graph_ids[i] : -1;
        if (!valid) {
            n = 0.0f;
#pragma unroll
            for (int m = 0; m < 10; ++m) he[m] = 0.0f;
        }

        int gid0 = __shfl(gid, 0, 64);
        bool allsame = __all(gid == gid0) && (gid0 >= 0);
        if (allsame) {
            float vv = n;
#pragma unroll
            for (int off = 32; off > 0; off >>= 1) vv += __shfl_down(vv, off, 64);
            float vh[10];
#pragma unroll
            for (int m = 0; m < 10; ++m) {
                float ww = he[m];
#pragma unroll
                for (int off = 32; off > 0; off >>= 1) ww += __shfl_down(ww, off, 64);
                vh[m] = ww;
            }
            if ((tid & 63) == 0) {
                int off = gid0 - gidBase;
                if (off >= 0 && off < 32) {
                    atomicAdd(&garr[off * 11 + 0], vv);
#pragma unroll
                    for (int m = 0; m < 10; ++m) atomicAdd(&garr[off * 11 + 1 + m], vh[m]);
                } else {
                    atomAddF(&graph_acc[gid0 * 11 + 0], vv);
#pragma unroll
                    for (int m = 0; m < 10; ++m) atomAddF(&graph_acc[gid0 * 11 + 1 + m], vh[m]);
                }
            }
        } else if (valid) {
            int off = gid - gidBase;
            if (off >= 0 && off < 32) {
                atomicAdd(&garr[off * 11 + 0], n);
#pragma unroll
                for (int m = 0; m < 10; ++m) atomicAdd(&garr[off * 11 + 1 + m], he[m]);
            } else {
                atomAddF(&graph_acc[gid * 11 + 0], n);
#pragma unroll
                for (int m = 0; m < 10; ++m) atomAddF(&graph_acc[gid * 11 + 1 + m], he[m]);
            }
        }
    }
    __syncthreads();

    // plain-store partials: graph spans <=2 consecutive blocks -> parity slot
    int ngl = gidEnd - gidBase + 1;
    if (ngl > 32) ngl = 32;
    int par = (b & 1) * 11000;
    for (int t = tid; t < ngl * 11; t += 1024) {
        int off = t / 11, f = t - off * 11;
        partials[par + (gidBase + off) * 11 + f] = garr[t];
    }
}

// ---------------- fallback path (ws too small) ----------------

__global__ __launch_bounds__(256) void k_zero(float* __restrict__ ws, int len4) {
    int i = blockIdx.x * 256 + threadIdx.x;
    if (i < len4) ((float4*)ws)[i] = make_float4(0.f, 0.f, 0.f, 0.f);
}

__global__ __launch_bounds__(256) void k_edges(
        const float* __restrict__ nodes, const float* __restrict__ edges,
        const int* __restrict__ senders, const int* __restrict__ receivers,
        const float* __restrict__ fw, float* __restrict__ node_acc) {
    float w_pn1[20], b_pn1[10], W_eb[50], b_eb[5], w1r0[5], w2e[5];
#pragma unroll
    for (int j = 0; j < 20; ++j) w_pn1[j] = fw[j];
#pragma unroll
    for (int j = 0; j < 10; ++j) b_pn1[j] = fw[20 + j];
#pragma unroll
    for (int j = 0; j < 50; ++j) W_eb[j] = fw[30 + j];
#pragma unroll
    for (int j = 0; j < 5; ++j) b_eb[j] = fw[80 + j];
#pragma unroll
    for (int j = 0; j < 5; ++j) w1r0[j] = fw[85 + j];
#pragma unroll
    for (int j = 0; j < 5; ++j) w2e[j] = fw[90 + j];
    float b2e = fw[95];

    int g = blockIdx.x * 256 + threadIdx.x;
    if (g >= NGROUPS_C) return;

    float4 e4 = ((const float4*)edges)[g];
    int4  s4 = ((const int4*)senders)[g];
    int4  r4 = ((const int4*)receivers)[g];
    float ev[4] = {e4.x, e4.y, e4.z, e4.w};
    int   sv[4] = {s4.x, s4.y, s4.z, s4.w};
    int   rv[4] = {r4.x, r4.y, r4.z, r4.w};
    float nsv[4], nrv[4];
#pragma unroll
    for (int u = 0; u < 4; ++u) { nsv[u] = nodes[sv[u]]; nrv[u] = nodes[rv[u]]; }
#pragma unroll
    for (int u = 0; u < 4; ++u) {
        float nr = nrv[u], ns = nsv[u];
        float bs[5];
#pragma unroll
        for (int k = 0; k < 5; ++k) bs[k] = b_eb[k];
#pragma unroll
        for (int j = 0; j < 10; ++j) {
            float zl = fmaf(nr, w_pn1[j], fmaf(ns, w_pn1[10 + j], b_pn1[j]));
            float sz = selu2(zl);
#pragma unroll
            for (int k = 0; k < 5; ++k) bs[k] = fmaf(sz, W_eb[j * 5 + k], bs[k]);
        }
        float e = ev[u];
#pragma unroll
        for (int it = 0; it < 3; ++it) {
            float acc2 = b2e;
#pragma unroll
            for (int k = 0; k < 5; ++k) {
                float tt = selu2(fmaf(e, w1r0[k], bs[k]));
                acc2 = fmaf(tt, w2e[k], acc2);
            }
            e = acc2;
        }
        atomAddF(&node_acc[rv[u]], e);
    }
}

__global__ __launch_bounds__(256) void k_nodes(
        const float* __restrict__ nodes, const int* __restrict__ graph_ids,
        const float* __restrict__ fw, const float* __restrict__ node_acc,
        float* __restrict__ graph_acc) {
    float w_pe1[5], b_pe1[5], pe_w2[50], pe_b2[10], W_nb[25], b_nb[5], w1r0n[5], w2n[5];
#pragma unroll
    for (int j = 0; j < 5; ++j) w_pe1[j] = fw[96 + j];
#pragma unroll
    for (int j = 0; j < 5; ++j) b_pe1[j] = fw[101 + j];
#pragma unroll
    for (int j = 0; j < 50; ++j) pe_w2[j] = fw[106 + j];
#pragma unroll
    for (int j = 0; j < 10; ++j) pe_b2[j] = fw[156 + j];
#pragma unroll
    for (int j = 0; j < 25; ++j) W_nb[j] = fw[166 + j];
#pragma unroll
    for (int j = 0; j < 5; ++j) b_nb[j] = fw[191 + j];
#pragma unroll
    for (int j = 0; j < 5; ++j) w1r0n[j] = fw[196 + j];
#pragma unroll
    for (int j = 0; j < 5; ++j) w2n[j] = fw[201 + j];
    float b2n = fw[206];

    int i = blockIdx.x * 256 + threadIdx.x;
    bool valid = i < N_NODES_C;
    int ii = valid ? i : (N_NODES_C - 1);

    float s = node_acc[ii];
    float t5[5];
#pragma unroll
    for (int k = 0; k < 5; ++k) t5[k] = selu2(fmaf(s, w_pe1[k], b_pe1[k]));
    float he[10];
#pragma unroll
    for (int m = 0; m < 10; ++m) {
        float a = pe_b2[m];
#pragma unroll
        for (int k = 0; k < 5; ++k) a = fmaf(t5[k], pe_w2[k * 10 + m], a);
        he[m] = a;
    }
    float bs[5];
#pragma unroll
    for (int k = 0; k < 5; ++k) {
        float a = b_nb[k];
#pragma unroll
        for (int t = 0; t < 5; ++t) a = fmaf(t5[t], W_nb[t * 5 + k], a);
        bs[k] = a;
    }
    float n = nodes[ii];
#pragma unroll
    for (int it = 0; it < 3; ++it) {
        float a = b2n;
#pragma unroll
        for (int k = 0; k < 5; ++k) {
            float tt = selu2(fmaf(n, w1r0n[k], bs[k]));
            a = fmaf(tt, w2n[k], a);
        }
        n = a;
    }

    int gid = valid ? graph_ids[ii] : -1;
    if (!valid) {
        n = 0.0f;
#pragma unroll
        for (int m = 0; m < 10; ++m) he[m] = 0.0f;
    }

    int gid0 = __shfl(gid, 0, 64);
    bool allsame = __all(gid == gid0) && (gid0 >= 0);
    if (allsame) {
        float v = n;
#pragma unroll
        for (int off = 32; off > 0; off >>= 1) v += __shfl_down(v, off, 64);
        float vh[10];
#pragma unroll
        for (int m = 0; m < 10; ++m) {
            float ww = he[m];
#pragma unroll
            for (int off = 32; off > 0; off >>= 1) ww += __shfl_down(ww, off, 64);
            vh[m] = ww;
        }
        if ((threadIdx.x & 63) == 0) {
            atomAddF(&graph_acc[gid0 * 11 + 0], v);
#pragma unroll
            for (int m = 0; m < 10; ++m) atomAddF(&graph_acc[gid0 * 11 + 1 + m], vh[m]);
        }
    } else if (valid) {
        atomAddF(&graph_acc[gid * 11 + 0], n);
#pragma unroll
        for (int m = 0; m < 10; ++m) atomAddF(&graph_acc[gid * 11 + 1 + m], he[m]);
    }
}

// ---------------- launch ----------------

extern "C" void kernel_launch(void* const* d_in, const int* in_sizes, int n_in,
                              void* d_out, int out_size, void* d_ws, size_t ws_size,
                              hipStream_t stream) {
    const float* nodes     = (const float*)d_in[0];
    const float* edges     = (const float*)d_in[1];
    const int*   senders   = (const int*)d_in[2];
    const int*   receivers = (const int*)d_in[3];
    const int*   graph_ids = (const int*)d_in[4];
    const float* pn_w1 = (const float*)d_in[6];
    const float* pn_b1 = (const float*)d_in[7];
    const float* pn_w2 = (const float*)d_in[8];
    const float* pn_b2 = (const float*)d_in[9];
    const float* ue_w1 = (const float*)d_in[10];
    const float* ue_b1 = (const float*)d_in[11];
    const float* ue_w2 = (const float*)d_in[12];
    const float* ue_b2 = (const float*)d_in[13];
    const float* pe_w1 = (const float*)d_in[14];
    const float* pe_b1 = (const float*)d_in[15];
    const float* pe_w2 = (const float*)d_in[16];
    const float* pe_b2 = (const float*)d_in[17];
    const float* un_w1 = (const float*)d_in[18];
    const float* un_b1 = (const float*)d_in[19];
    const float* un_w2 = (const float*)d_in[20];
    const float* un_b2 = (const float*)d_in[21];
    const float* pr_w1 = (const float*)d_in[22];
    const float* pr_b1 = (const float*)d_in[23];
    const float* pr_w2 = (const float*)d_in[24];
    const float* pr_b2 = (const float*)d_in[25];

    float* ws        = (float*)d_ws;
    float* graph_acc = ws + GRAPH_ACC_OFF;
    float* partials  = ws + PARTIALS_OFF;
    float* fw        = ws + FW_OFF;
    float* outp      = (float*)d_out;

    if (ws_size >= (size_t)WS2_WORDS_NEEDED * 4) {
        // main path: sort-first, MLP-in-gather (r3 champion + fused init,
        // batch-2 gather loop). 3 launches.
        int* starts_T = (int*)ws + STARTS2_OFF;
        unsigned long long* pairs64 = (unsigned long long*)((int*)ws + PAIRS64_OFF);

        hipLaunchKernelGGL(k_part2, dim3(NPB2), dim3(P2_TPB), 0, stream,
                           ws, edges, senders, receivers, starts_T, pairs64,
                           pn_w1, pn_b1, pn_w2, pn_b2, ue_w1, ue_b1, ue_w2, ue_b2,
                           pe_w1, pe_b1, pe_w2, pe_b2, un_w1, un_b1, un_w2, un_b2);
        hipLaunchKernelGGL(k_gather2, dim3(NBKT), dim3(1024), 0, stream,
                           nodes, graph_ids, fw, starts_T, pairs64, graph_acc, partials);
        hipLaunchKernelGGL(k_final, dim3((N_GRAPHS_C + 255) / 256), dim3(256), 0, stream,
                           graph_acc, partials, pr_w1, pr_b1, pr_w2, pr_b2, outp);
    } else {
        float* node_acc = ws + OLD_NODE_ACC_OFF;
        int len4 = OLD_ZERO_WORDS / 4;
        hipLaunchKernelGGL(k_zero, dim3((len4 + 255) / 256), dim3(256), 0, stream, ws, len4);
        hipLaunchKernelGGL(k_fuse, dim3(1), dim3(64), 0, stream,
                           pn_w1, pn_b1, pn_w2, pn_b2, ue_w1, ue_b1, ue_w2, ue_b2,
                           pe_w1, pe_b1, pe_w2, pe_b2, un_w1, un_b1, un_w2, un_b2, fw);
        hipLaunchKernelGGL(k_edges, dim3((NGROUPS_C + 255) / 256), dim3(256), 0, stream,
                           nodes, edges, senders, receivers, fw, node_acc);
        hipLaunchKernelGGL(k_nodes, dim3((N_NODES_C + 255) / 256), dim3(256), 0, stream,
                           nodes, graph_ids, fw, node_acc, graph_acc);
        hipLaunchKernelGGL(k_final, dim3((N_GRAPHS_C + 255) / 256), dim3(256), 0, stream,
                           graph_acc, partials, pr_w1, pr_b1, pr_w2, pr_b2, outp);
    }
}

// Round 9
// 282.559 us; speedup vs baseline: 2.3747x; 1.0630x over previous
//
#include <hip/hip_runtime.h>
#include <hip/hip_fp16.h>
#include <math.h>

#define N_NODES_C  500000
#define N_EDGES_C  8000000
#define N_GRAPHS_C 1000
#define NGROUPS_C  (N_EDGES_C / 4)     // 2,000,000 float4-groups

#define BSHIFT  11                     // bucket = recv >> 11
#define BWIDTH  2048
#define NBKT    245                    // ceil(500000 / 2048)

#define P2_TPB  512
#define EPB2    8192                   // edges per part-block (64KB staged u64)
#define GPB2    (EPB2 / 4)             // 2048 groups
#define NPB2    ((NGROUPS_C + GPB2 - 1) / GPB2) // 977
#define SROW2   992
#define RITER2  (GPB2 / P2_TPB)        // 4
#define HALF_P  489                    // parts per half (h=0: 489, h=1: 488)

// ---- workspace layout (32-bit word offsets) ----
#define GRAPH_ACC_OFF 0                          // 11000 floats
#define PARTIALS_OFF  11008                      // 2*11000 floats
#define FW_OFF        33024                      // 207 floats fused weights
#define ZERO_HEAD     33024                      // graph_acc + partials

#define STARTS2_OFF   33280                      // 246 * SROW2 ints
#define PAIRS64_OFF   (STARTS2_OFF + 246 * SROW2)        // 277312; *4%16==0
#define WS2_WORDS_NEEDED (PAIRS64_OFF + NPB2 * EPB2 * 2) // 16,284,480 (65.1MB)

// tier-1 extra: two partial node-acc halves (plain stores, no atomics)
#define NA2_STRIDE    (NBKT * BWIDTH)                    // 501,760 floats/half
#define NODEACC2_OFF  WS2_WORDS_NEEDED                   // 16,284,480
#define WS3_WORDS_NEEDED (NODEACC2_OFF + 2 * NA2_STRIDE) // 17,288,000 (69.15MB)

// fallback layout
#define OLD_NODE_ACC_OFF 33536
#define OLD_ZERO_WORDS   (OLD_NODE_ACC_OFF + N_NODES_C)

#define LOG2E_F 1.4426950408889634f

// fused-weight layout inside fw[]; (L) = pre-scaled by log2(e):
// 0:w_pn1[20](L) 20:b_pn1[10](L) 30:W_eb[50](L) 80:b_eb[5](L) 85:w1r0_e[5](L)
// 90:w2_e[5] 95:b2_e
// 96:w_pe1[5](L) 101:b_pe1[5](L) 106:pe_w2[50] 156:pe_b2[10]
// 166:W_nb[25](L) 191:b_nb[5](L) 196:w1r0_n[5](L) 201:w2_n[5] 206:b2_n

__device__ __forceinline__ float selu2(float xl) {
    const float C1 = 0.7282901039f;        // 1.0507009873554805 * ln(2)
    const float C2 = 1.7580993408473766f;  // scale * alpha
    float e = __builtin_amdgcn_exp2f(xl);
    float neg = fmaf(C2, e, -C2);
    return xl > 0.0f ? C1 * xl : neg;
}

__device__ __forceinline__ float selu_f(float x) {
    const float scale = 1.0507009873554805f;
    const float sa    = 1.0507009873554805f * 1.6732632423543772f;
    float neg = sa * (__expf(x) - 1.0f);
    return x > 0.0f ? scale * x : neg;
}

__device__ __forceinline__ void atomAddF(float* p, float v) {
    __hip_atomic_fetch_add(p, v, __ATOMIC_RELAXED, __HIP_MEMORY_SCOPE_AGENT);
}

__device__ __forceinline__ void fuse_weights(
        int t,
        const float* __restrict__ pn_w1, const float* __restrict__ pn_b1,
        const float* __restrict__ pn_w2, const float* __restrict__ pn_b2,
        const float* __restrict__ ue_w1, const float* __restrict__ ue_b1,
        const float* __restrict__ ue_w2, const float* __restrict__ ue_b2,
        const float* __restrict__ pe_w1, const float* __restrict__ pe_b1,
        const float* __restrict__ pe_w2, const float* __restrict__ pe_b2,
        const float* __restrict__ un_w1, const float* __restrict__ un_b1,
        const float* __restrict__ un_w2, const float* __restrict__ un_b2,
        float* __restrict__ fw) {
    const float L = LOG2E_F;
    if (t < 20) fw[0 + t] = pn_w1[t] * L;
    if (t < 10) fw[20 + t] = pn_b1[t] * L;
    if (t < 50) {
        int j = t / 5, k = t % 5;
        float s = 0.0f;
        for (int m = 0; m < 10; ++m) s += pn_w2[j * 10 + m] * ue_w1[(1 + m) * 5 + k];
        fw[30 + t] = s * L;
    }
    if (t < 5) {
        float s = ue_b1[t];
        for (int m = 0; m < 10; ++m) s += pn_b2[m] * ue_w1[(1 + m) * 5 + t];
        fw[80 + t] = s * L;
    }
    if (t < 5)  fw[85 + t]  = ue_w1[t] * L;
    if (t < 5)  fw[90 + t]  = ue_w2[t];
    if (t == 0) fw[95]      = ue_b2[0];
    if (t < 5)  fw[96 + t]  = pe_w1[t] * L;
    if (t < 5)  fw[101 + t] = pe_b1[t] * L;
    if (t < 50) fw[106 + t] = pe_w2[t];
    if (t < 10) fw[156 + t] = pe_b2[t];
    if (t < 25) {
        int j = t / 5, k = t % 5;
        float s = 0.0f;
        for (int m = 0; m < 10; ++m) s += pe_w2[j * 10 + m] * un_w1[(1 + m) * 5 + k];
        fw[166 + t] = s * L;
    }
    if (t < 5) {
        float s = un_b1[t];
        for (int m = 0; m < 10; ++m) s += pe_b2[m] * un_w1[(1 + m) * 5 + t];
        fw[191 + t] = s * L;
    }
    if (t < 5)  fw[196 + t] = un_w1[t] * L;
    if (t < 5)  fw[201 + t] = un_w2[t];
    if (t == 0) fw[206]     = un_b2[0];
}

__global__ void k_fuse(const float* pn_w1, const float* pn_b1, const float* pn_w2, const float* pn_b2,
                       const float* ue_w1, const float* ue_b1, const float* ue_w2, const float* ue_b2,
                       const float* pe_w1, const float* pe_b1, const float* pe_w2, const float* pe_b2,
                       const float* un_w1, const float* un_b1, const float* un_w2, const float* un_b2,
                       float* fw) {
    fuse_weights(threadIdx.x, pn_w1, pn_b1, pn_w2, pn_b2, ue_w1, ue_b1, ue_w2, ue_b2,
                 pe_w1, pe_b1, pe_w2, pe_b2, un_w1, un_b1, un_w2, un_b2, fw);
}

__global__ void k_final(const float* __restrict__ graph_acc,
                        const float* __restrict__ partials,
                        const float* __restrict__ pr_w1, const float* __restrict__ pr_b1,
                        const float* __restrict__ pr_w2, const float* __restrict__ pr_b2,
                        float* __restrict__ out) {
    int g = blockIdx.x * blockDim.x + threadIdx.x;
    if (g >= N_GRAPHS_C) return;
    float gv[11];
#pragma unroll
    for (int f = 0; f < 11; ++f)
        gv[f] = graph_acc[g * 11 + f] + partials[g * 11 + f] + partials[11000 + g * 11 + f];
    float h[10];
#pragma unroll
    for (int j = 0; j < 10; ++j) {
        float z = pr_b1[j];
#pragma unroll
        for (int f = 0; f < 11; ++f) z = fmaf(gv[f], pr_w1[f * 10 + j], z);
        h[j] = selu_f(z);
    }
    float o[10];
    float mx = -1e30f;
#pragma unroll
    for (int j = 0; j < 10; ++j) {
        float z = pr_b2[j];
#pragma unroll
        for (int m = 0; m < 10; ++m) z = fmaf(h[m], pr_w2[m * 10 + j], z);
        o[j] = z;
        mx = fmaxf(mx, z);
    }
    float sum = 0.0f;
#pragma unroll
    for (int j = 0; j < 10; ++j) { o[j] = __expf(o[j] - mx); sum += o[j]; }
    float inv = 1.0f / sum;
#pragma unroll
    for (int j = 0; j < 10; ++j) out[g * 10 + j] = o[j] * inv;
}

// ==================== main path: sort-first, MLP-in-gather ====================

// k_part2: streaming counting sort ONLY (no MLP, no node gathers).
// Packs u64 {recv_local:11 @bit51 | sender:19 @bit32 | edge f32 @bit0}.
// Fused init: each block zeros a 34-word slice of graph_acc/partials;
// block 0 additionally builds the fused weights (consumed next kernel).
__global__ __launch_bounds__(P2_TPB) void k_part2(
        float* __restrict__ ws,
        const float* __restrict__ edges,
        const int* __restrict__ senders, const int* __restrict__ receivers,
        int* __restrict__ starts_T, unsigned long long* __restrict__ pairs64,
        const float* pn_w1, const float* pn_b1, const float* pn_w2, const float* pn_b2,
        const float* ue_w1, const float* ue_b1, const float* ue_w2, const float* ue_b2,
        const float* pe_w1, const float* pe_b1, const float* pe_w2, const float* pe_b2,
        const float* un_w1, const float* un_b1, const float* un_w2, const float* un_b2) {
    __shared__ int hist[256];
    __shared__ int cursorS[256];
    __shared__ alignas(16) unsigned long long staged[EPB2];   // 64 KB

    int tid = threadIdx.x;
    int p   = blockIdx.x;

    // fused init
    if (tid < 34) {
        int z = p * 34 + tid;
        if (z < ZERO_HEAD) ws[z] = 0.0f;
    }
    if (p == 0)
        fuse_weights(tid, pn_w1, pn_b1, pn_w2, pn_b2, ue_w1, ue_b1, ue_w2, ue_b2,
                     pe_w1, pe_b1, pe_w2, pe_b2, un_w1, un_b1, un_w2, un_b2, ws + FW_OFF);

    int gstart = p * GPB2;
    int gnum   = NGROUPS_C - gstart;
    if (gnum > GPB2) gnum = GPB2;

    if (tid < 256) hist[tid] = 0;
    __syncthreads();

    // phase A: load receivers (kept in regs), histogram
    int4 rv4[RITER2];
#pragma unroll
    for (int r = 0; r < RITER2; ++r) {
        int idx = r * P2_TPB + tid;
        int gi  = gstart + (idx < gnum ? idx : 0);
        rv4[r] = ((const int4*)receivers)[gi];
        if (idx < gnum) {
            atomicAdd(&hist[rv4[r].x >> BSHIFT], 1);
            atomicAdd(&hist[rv4[r].y >> BSHIFT], 1);
            atomicAdd(&hist[rv4[r].z >> BSHIFT], 1);
            atomicAdd(&hist[rv4[r].w >> BSHIFT], 1);
        }
    }
    __syncthreads();

    // inclusive scan over 256 buckets (tids 0..255 active)
    int orig = 0, val = 0;
    if (tid < 256) { orig = hist[tid]; val = orig; }
    for (int d = 1; d < 256; d <<= 1) {
        int add = 0;
        if (tid >= d && tid < 256) add = hist[tid - d];
        __syncthreads();
        if (tid >= d && tid < 256) { val += add; hist[tid] = val; }
        __syncthreads();
    }
    int excl = val - orig;
    if (tid < 256) cursorS[tid] = excl;
    if (tid < 246) starts_T[tid * SROW2 + p] = excl;
    __syncthreads();

    // phase C: pack + counting sort into LDS
#pragma unroll
    for (int r = 0; r < RITER2; ++r) {
        int idx = r * P2_TPB + tid;
        int gi  = gstart + (idx < gnum ? idx : 0);
        float4 e4 = ((const float4*)edges)[gi];
        int4   s4 = ((const int4*)senders)[gi];
        int4   rv = rv4[r];
        if (idx < gnum) {
            int   rvv[4] = {rv.x, rv.y, rv.z, rv.w};
            int   svv[4] = {s4.x, s4.y, s4.z, s4.w};
            float evv[4] = {e4.x, e4.y, e4.z, e4.w};
#pragma unroll
            for (int u = 0; u < 4; ++u) {
                int bkt  = rvv[u] >> BSHIFT;
                int slot = atomicAdd(&cursorS[bkt], 1);
                unsigned long long pk =
                    ((unsigned long long)(rvv[u] & (BWIDTH - 1)) << 51)
                  | ((unsigned long long)(unsigned)svv[u] << 32)
                  | (unsigned long long)__float_as_uint(evv[u]);
                staged[slot] = pk;
            }
        }
    }
    __syncthreads();

    // flush: contiguous uint4 stores (gnum*4 u64 = gnum*2 uint4)
    const uint4* st4 = (const uint4*)staged;
    uint4* dst = (uint4*)(pairs64 + (size_t)p * EPB2);
    int n4 = gnum * 2;
    for (int i = tid; i < n4; i += P2_TPB) dst[i] = st4[i];
}

// shared edge-MLP body (single-item, r3-proven form)
#define EDGE_MLP_BODY(pk, accf)                                              \
    {                                                                        \
        int   rl   = (int)((pk) >> 51);                                      \
        int   sidx = (int)(((pk) >> 32) & 0x7FFFFULL);                       \
        float e    = __uint_as_float((unsigned)(pk));                        \
        float nr   = nf[rl];                                                 \
        float ns   = nodes[sidx];                                            \
        float bs[5];                                                         \
        _Pragma("unroll")                                                    \
        for (int k = 0; k < 5; ++k) bs[k] = b_eb[k];                         \
        _Pragma("unroll")                                                    \
        for (int j = 0; j < 10; ++j) {                                       \
            float zl = fmaf(nr, w_pn1[j], fmaf(ns, w_pn1[10 + j], b_pn1[j]));\
            float sz = selu2(zl);                                            \
            _Pragma("unroll")                                                \
            for (int k = 0; k < 5; ++k) bs[k] = fmaf(sz, W_eb[j*5+k], bs[k]);\
        }                                                                    \
        _Pragma("unroll")                                                    \
        for (int it = 0; it < 3; ++it) {                                     \
            float acc2 = b2e;                                                \
            _Pragma("unroll")                                                \
            for (int k = 0; k < 5; ++k) {                                    \
                float tt = selu2(fmaf(e, w1r0[k], bs[k]));                   \
                acc2 = fmaf(tt, w2e[k], acc2);                               \
            }                                                                \
            e = acc2;                                                        \
        }                                                                    \
        atomicAdd(&(accf)[rl], e);                                           \
    }

// k_gather2s (tier-1): TWO blocks per bucket, split along the PART axis
// (h=0: parts 0..488, h=1: parts 489..976). Segment geometry and FETCH are
// identical to the proven r3 kernel, but block count doubles (490) so the
// 1-block/CU occupancy cap (16 waves) becomes 2 blocks/CU (32 waves).
// Each half accumulates a partial accf in LDS and plain-stores it.
__global__ __launch_bounds__(1024, 8) void k_gather2s(
        const float* __restrict__ nodes,
        const float* __restrict__ fw, const int* __restrict__ starts_T,
        const unsigned long long* __restrict__ pairs64,
        float* __restrict__ nodeacc2) {
    __shared__ float accf[BWIDTH];        // 8 KB
    __shared__ float nf[BWIDTH];          // 8 KB
    __shared__ int   s0[HALF_P];          // 1.9 KB
    __shared__ int   pst[HALF_P + 1];     // 1.9 KB
    __shared__ int   sc[512];             // 2 KB
    int tid = threadIdx.x;
    int b   = blockIdx.x >> 1;
    int h   = blockIdx.x & 1;
    int pbase  = h * HALF_P;
    int pcount = h ? (NPB2 - HALF_P) : HALF_P;   // 488 or 489

    int nodeBase = b << BSHIFT;
    int lastIdx  = nodeBase + BWIDTH;
    if (lastIdx > N_NODES_C) lastIdx = N_NODES_C;
    int lim = lastIdx - nodeBase;

    accf[tid] = 0.0f; accf[1024 + tid] = 0.0f;
    nf[tid]        = (tid        < lim) ? nodes[nodeBase + tid]        : 0.0f;
    nf[1024 + tid] = (1024 + tid < lim) ? nodes[nodeBase + 1024 + tid] : 0.0f;

    int cntv = 0;
    if (tid < pcount) {
        int a = starts_T[b * SROW2 + pbase + tid];
        int c = starts_T[(b + 1) * SROW2 + pbase + tid];
        s0[tid] = a;
        cntv = c - a;
    }
    if (tid < 512) sc[tid] = cntv;
    __syncthreads();

    // inclusive scan over 512 (pcount real + zero pad), threads 0..511
    int v = cntv;
    for (int d = 1; d < 512; d <<= 1) {
        int add = (tid >= d && tid < 512) ? sc[tid - d] : 0;
        __syncthreads();
        if (tid >= d && tid < 512) { v += add; sc[tid] = v; }
        __syncthreads();
    }
    if (tid == 0) pst[0] = 0;
    if (tid < pcount) pst[tid + 1] = v;
    __syncthreads();

    int M = pst[pcount];   // edges for this bucket-half

    {
        float w_pn1[20], b_pn1[10], W_eb[50], b_eb[5], w1r0[5], w2e[5];
#pragma unroll
        for (int j = 0; j < 20; ++j) w_pn1[j] = fw[j];
#pragma unroll
        for (int j = 0; j < 10; ++j) b_pn1[j] = fw[20 + j];
#pragma unroll
        for (int j = 0; j < 50; ++j) W_eb[j] = fw[30 + j];
#pragma unroll
        for (int j = 0; j < 5; ++j) b_eb[j] = fw[80 + j];
#pragma unroll
        for (int j = 0; j < 5; ++j) w1r0[j] = fw[85 + j];
#pragma unroll
        for (int j = 0; j < 5; ++j) w2e[j] = fw[90 + j];
        float b2e = fw[95];

#pragma unroll 1
        for (int i = tid; i < M; i += 1024) {
            // 9-step search over <=489 segments: largest lo with pst[lo]<=i
            int lo = 0, hi = pcount;
#pragma unroll
            for (int s = 0; s < 9; ++s) {
                int mid = (lo + hi) >> 1;
                if (pst[mid] <= i) lo = mid; else hi = mid;
            }
            unsigned long long pk =
                pairs64[(size_t)(pbase + lo) * EPB2 + s0[lo] + (i - pst[lo])];
            EDGE_MLP_BODY(pk, accf)
        }
    }
    __syncthreads();

    // flush partial accf (coalesced plain stores; no atomics)
    float* dst = nodeacc2 + (size_t)h * NA2_STRIDE + (size_t)b * BWIDTH;
    dst[tid] = accf[tid];
    dst[1024 + tid] = accf[1024 + tid];
}

// k_nodes2 (tier-1): sum the two partial halves, node MLP + graph reduction
// with parity-partials (proven epilogue; one block per bucket).
__global__ __launch_bounds__(1024) void k_nodes2(
        const float* __restrict__ nodes, const int* __restrict__ graph_ids,
        const float* __restrict__ fw, const float* __restrict__ nodeacc2,
        float* __restrict__ graph_acc, float* __restrict__ partials) {
    __shared__ float garr[32 * 11];
    int tid = threadIdx.x;
    int b   = blockIdx.x;

    if (tid < 352) garr[tid] = 0.0f;

    float w_pe1[5], b_pe1[5], pe_w2[50], pe_b2[10], W_nb[25], b_nb[5], w1r0n[5], w2n[5];
#pragma unroll
    for (int j = 0; j < 5; ++j) w_pe1[j] = fw[96 + j];
#pragma unroll
    for (int j = 0; j < 5; ++j) b_pe1[j] = fw[101 + j];
#pragma unroll
    for (int j = 0; j < 50; ++j) pe_w2[j] = fw[106 + j];
#pragma unroll
    for (int j = 0; j < 10; ++j) pe_b2[j] = fw[156 + j];
#pragma unroll
    for (int j = 0; j < 25; ++j) W_nb[j] = fw[166 + j];
#pragma unroll
    for (int j = 0; j < 5; ++j) b_nb[j] = fw[191 + j];
#pragma unroll
    for (int j = 0; j < 5; ++j) w1r0n[j] = fw[196 + j];
#pragma unroll
    for (int j = 0; j < 5; ++j) w2n[j] = fw[201 + j];
    float b2n = fw[206];

    int nodeBase = b << BSHIFT;
    int lastIdx  = nodeBase + BWIDTH;
    if (lastIdx > N_NODES_C) lastIdx = N_NODES_C;
    int gidBase = graph_ids[nodeBase];
    int gidEnd  = graph_ids[lastIdx - 1];
    __syncthreads();

#pragma unroll
    for (int q = 0; q < 2; ++q) {
        int local = q * 1024 + tid;
        int i = nodeBase + local;
        bool valid = i < N_NODES_C;

        float s = nodeacc2[(size_t)b * BWIDTH + local]
                + nodeacc2[(size_t)NA2_STRIDE + (size_t)b * BWIDTH + local];
        float t5[5];
#pragma unroll
        for (int k = 0; k < 5; ++k) t5[k] = selu2(fmaf(s, w_pe1[k], b_pe1[k]));
        float he[10];
#pragma unroll
        for (int m = 0; m < 10; ++m) {
            float a = pe_b2[m];
#pragma unroll
            for (int k = 0; k < 5; ++k) a = fmaf(t5[k], pe_w2[k * 10 + m], a);
            he[m] = a;
        }
        float bs[5];
#pragma unroll
        for (int k = 0; k < 5; ++k) {
            float a = b_nb[k];
#pragma unroll
            for (int t = 0; t < 5; ++t) a = fmaf(t5[t], W_nb[t * 5 + k], a);
            bs[k] = a;
        }
        float n = valid ? nodes[i] : 0.0f;
#pragma unroll
        for (int it = 0; it < 3; ++it) {
            float a = b2n;
#pragma unroll
            for (int k = 0; k < 5; ++k) {
                float tt = selu2(fmaf(n, w1r0n[k], bs[k]));
                a = fmaf(tt, w2n[k], a);
            }
            n = a;
        }

        int gid = valid ? graph_ids[i] : -1;
        if (!valid) {
            n = 0.0f;
#pragma unroll
            for (int m = 0; m < 10; ++m) he[m] = 0.0f;
        }

        int gid0 = __shfl(gid, 0, 64);
        bool allsame = __all(gid == gid0) && (gid0 >= 0);
        if (allsame) {
            float vv = n;
#pragma unroll
            for (int off = 32; off > 0; off >>= 1) vv += __shfl_down(vv, off, 64);
            float vh[10];
#pragma unroll
            for (int m = 0; m < 10; ++m) {
                float ww = he[m];
#pragma unroll
                for (int off = 32; off > 0; off >>= 1) ww += __shfl_down(ww, off, 64);
                vh[m] = ww;
            }
            if ((tid & 63) == 0) {
                int off = gid0 - gidBase;
                if (off >= 0 && off < 32) {
                    atomicAdd(&garr[off * 11 + 0], vv);
#pragma unroll
                    for (int m = 0; m < 10; ++m) atomicAdd(&garr[off * 11 + 1 + m], vh[m]);
                } else {
                    atomAddF(&graph_acc[gid0 * 11 + 0], vv);
#pragma unroll
                    for (int m = 0; m < 10; ++m) atomAddF(&graph_acc[gid0 * 11 + 1 + m], vh[m]);
                }
            }
        } else if (valid) {
            int off = gid - gidBase;
            if (off >= 0 && off < 32) {
                atomicAdd(&garr[off * 11 + 0], n);
#pragma unroll
                for (int m = 0; m < 10; ++m) atomicAdd(&garr[off * 11 + 1 + m], he[m]);
            } else {
                atomAddF(&graph_acc[gid * 11 + 0], n);
#pragma unroll
                for (int m = 0; m < 10; ++m) atomAddF(&graph_acc[gid * 11 + 1 + m], he[m]);
            }
        }
    }
    __syncthreads();

    int ngl = gidEnd - gidBase + 1;
    if (ngl > 32) ngl = 32;
    int par = (b & 1) * 11000;
    for (int t = tid; t < ngl * 11; t += 1024) {
        int off = t / 11, f = t - off * 11;
        partials[par + (gidBase + off) * 11 + f] = garr[t];
    }
}

// k_gather2 (tier-2): exact r3-proven kernel — single-item loop, VGPR 32.
__global__ __launch_bounds__(1024) void k_gather2(
        const float* __restrict__ nodes, const int* __restrict__ graph_ids,
        const float* __restrict__ fw, const int* __restrict__ starts_T,
        const unsigned long long* __restrict__ pairs64,
        float* __restrict__ graph_acc, float* __restrict__ partials) {
    __shared__ float accf[BWIDTH];
    __shared__ float nf[BWIDTH];
    __shared__ int   s0[NPB2];
    __shared__ int   pst[NPB2 + 1];
    __shared__ int   sc[1024];
    __shared__ float garr[32 * 11];
    int tid = threadIdx.x;
    int b   = blockIdx.x;

    int nodeBase = b << BSHIFT;
    int lastIdx  = nodeBase + BWIDTH;
    if (lastIdx > N_NODES_C) lastIdx = N_NODES_C;
    int lim = lastIdx - nodeBase;

    accf[tid] = 0.0f; accf[1024 + tid] = 0.0f;
    nf[tid]        = (tid        < lim) ? nodes[nodeBase + tid]        : 0.0f;
    nf[1024 + tid] = (1024 + tid < lim) ? nodes[nodeBase + 1024 + tid] : 0.0f;
    if (tid < 352) garr[tid] = 0.0f;

    int cntv = 0;
    if (tid < NPB2) {
        int a = starts_T[b * SROW2 + tid];
        int c = starts_T[(b + 1) * SROW2 + tid];
        s0[tid] = a;
        cntv = c - a;
    }
    sc[tid] = cntv;
    __syncthreads();

    int v = cntv;
    for (int d = 1; d < 1024; d <<= 1) {
        int add = (tid >= d) ? sc[tid - d] : 0;
        __syncthreads();
        if (tid >= d) { v += add; sc[tid] = v; }
        __syncthreads();
    }
    if (tid == 0) pst[0] = 0;
    if (tid < NPB2) pst[tid + 1] = v;
    __syncthreads();

    int M = pst[NPB2];

    {
        float w_pn1[20], b_pn1[10], W_eb[50], b_eb[5], w1r0[5], w2e[5];
#pragma unroll
        for (int j = 0; j < 20; ++j) w_pn1[j] = fw[j];
#pragma unroll
        for (int j = 0; j < 10; ++j) b_pn1[j] = fw[20 + j];
#pragma unroll
        for (int j = 0; j < 50; ++j) W_eb[j] = fw[30 + j];
#pragma unroll
        for (int j = 0; j < 5; ++j) b_eb[j] = fw[80 + j];
#pragma unroll
        for (int j = 0; j < 5; ++j) w1r0[j] = fw[85 + j];
#pragma unroll
        for (int j = 0; j < 5; ++j) w2e[j] = fw[90 + j];
        float b2e = fw[95];

#pragma unroll 1
        for (int i = tid; i < M; i += 1024) {
            int lo = 0, hi = NPB2;
#pragma unroll
            for (int s = 0; s < 10; ++s) {
                int mid = (lo + hi) >> 1;
                if (pst[mid] <= i) lo = mid; else hi = mid;
            }
            unsigned long long pk =
                pairs64[(size_t)lo * EPB2 + s0[lo] + (i - pst[lo])];
            EDGE_MLP_BODY(pk, accf)
        }
    }
    __syncthreads();

    float w_pe1[5], b_pe1[5], pe_w2[50], pe_b2[10], W_nb[25], b_nb[5], w1r0n[5], w2n[5];
#pragma unroll
    for (int j = 0; j < 5; ++j) w_pe1[j] = fw[96 + j];
#pragma unroll
    for (int j = 0; j < 5; ++j) b_pe1[j] = fw[101 + j];
#pragma unroll
    for (int j = 0; j < 50; ++j) pe_w2[j] = fw[106 + j];
#pragma unroll
    for (int j = 0; j < 10; ++j) pe_b2[j] = fw[156 + j];
#pragma unroll
    for (int j = 0; j < 25; ++j) W_nb[j] = fw[166 + j];
#pragma unroll
    for (int j = 0; j < 5; ++j) b_nb[j] = fw[191 + j];
#pragma unroll
    for (int j = 0; j < 5; ++j) w1r0n[j] = fw[196 + j];
#pragma unroll
    for (int j = 0; j < 5; ++j) w2n[j] = fw[201 + j];
    float b2n = fw[206];

    int gidBase = graph_ids[nodeBase];
    int gidEnd  = graph_ids[lastIdx - 1];

#pragma unroll
    for (int q = 0; q < 2; ++q) {
        int local = q * 1024 + tid;
        int i = nodeBase + local;
        bool valid = i < N_NODES_C;

        float s = accf[local];
        float t5[5];
#pragma unroll
        for (int k = 0; k < 5; ++k) t5[k] = selu2(fmaf(s, w_pe1[k], b_pe1[k]));
        float he[10];
#pragma unroll
        for (int m = 0; m < 10; ++m) {
            float a = pe_b2[m];
#pragma unroll
            for (int k = 0; k < 5; ++k) a = fmaf(t5[k], pe_w2[k * 10 + m], a);
            he[m] = a;
        }
        float bs[5];
#pragma unroll
        for (int k = 0; k < 5; ++k) {
            float a = b_nb[k];
#pragma unroll
            for (int t = 0; t < 5; ++t) a = fmaf(t5[t], W_nb[t * 5 + k], a);
            bs[k] = a;
        }
        float n = valid ? nf[local] : 0.0f;
#pragma unroll
        for (int it = 0; it < 3; ++it) {
            float a = b2n;
#pragma unroll
            for (int k = 0; k < 5; ++k) {
                float tt = selu2(fmaf(n, w1r0n[k], bs[k]));
                a = fmaf(tt, w2n[k], a);
            }
            n = a;
        }

        int gid = valid ? graph_ids[i] : -1;
        if (!valid) {
            n = 0.0f;
#pragma unroll
            for (int m = 0; m < 10; ++m) he[m] = 0.0f;
        }

        int gid0 = __shfl(gid, 0, 64);
        bool allsame = __all(gid == gid0) && (gid0 >= 0);
        if (allsame) {
            float vv = n;
#pragma unroll
            for (int off = 32; off > 0; off >>= 1) vv += __shfl_down(vv, off, 64);
            float vh[10];
#pragma unroll
            for (int m = 0; m < 10; ++m) {
                float ww = he[m];
#pragma unroll
                for (int off = 32; off > 0; off >>= 1) ww += __shfl_down(ww, off, 64);
                vh[m] = ww;
            }
            if ((tid & 63) == 0) {
                int off = gid0 - gidBase;
                if (off >= 0 && off < 32) {
                    atomicAdd(&garr[off * 11 + 0], vv);
#pragma unroll
                    for (int m = 0; m < 10; ++m) atomicAdd(&garr[off * 11 + 1 + m], vh[m]);
                } else {
                    atomAddF(&graph_acc[gid0 * 11 + 0], vv);
#pragma unroll
                    for (int m = 0; m < 10; ++m) atomAddF(&graph_acc[gid0 * 11 + 1 + m], vh[m]);
                }
            }
        } else if (valid) {
            int off = gid - gidBase;
            if (off >= 0 && off < 32) {
                atomicAdd(&garr[off * 11 + 0], n);
#pragma unroll
                for (int m = 0; m < 10; ++m) atomicAdd(&garr[off * 11 + 1 + m], he[m]);
            } else {
                atomAddF(&graph_acc[gid * 11 + 0], n);
#pragma unroll
                for (int m = 0; m < 10; ++m) atomAddF(&graph_acc[gid * 11 + 1 + m], he[m]);
            }
        }
    }
    __syncthreads();

    int ngl = gidEnd - gidBase + 1;
    if (ngl > 32) ngl = 32;
    int par = (b & 1) * 11000;
    for (int t = tid; t < ngl * 11; t += 1024) {
        int off = t / 11, f = t - off * 11;
        partials[par + (gidBase + off) * 11 + f] = garr[t];
    }
}

// ---------------- fallback path (ws too small) ----------------

__global__ __launch_bounds__(256) void k_zero(float* __restrict__ ws, int len4) {
    int i = blockIdx.x * 256 + threadIdx.x;
    if (i < len4) ((float4*)ws)[i] = make_float4(0.f, 0.f, 0.f, 0.f);
}

__global__ __launch_bounds__(256) void k_edges(
        const float* __restrict__ nodes, const float* __restrict__ edges,
        const int* __restrict__ senders, const int* __restrict__ receivers,
        const float* __restrict__ fw, float* __restrict__ node_acc) {
    float w_pn1[20], b_pn1[10], W_eb[50], b_eb[5], w1r0[5], w2e[5];
#pragma unroll
    for (int j = 0; j < 20; ++j) w_pn1[j] = fw[j];
#pragma unroll
    for (int j = 0; j < 10; ++j) b_pn1[j] = fw[20 + j];
#pragma unroll
    for (int j = 0; j < 50; ++j) W_eb[j] = fw[30 + j];
#pragma unroll
    for (int j = 0; j < 5; ++j) b_eb[j] = fw[80 + j];
#pragma unroll
    for (int j = 0; j < 5; ++j) w1r0[j] = fw[85 + j];
#pragma unroll
    for (int j = 0; j < 5; ++j) w2e[j] = fw[90 + j];
    float b2e = fw[95];

    int g = blockIdx.x * 256 + threadIdx.x;
    if (g >= NGROUPS_C) return;

    float4 e4 = ((const float4*)edges)[g];
    int4  s4 = ((const int4*)senders)[g];
    int4  r4 = ((const int4*)receivers)[g];
    float ev[4] = {e4.x, e4.y, e4.z, e4.w};
    int   sv[4] = {s4.x, s4.y, s4.z, s4.w};
    int   rv[4] = {r4.x, r4.y, r4.z, r4.w};
    float nsv[4], nrv[4];
#pragma unroll
    for (int u = 0; u < 4; ++u) { nsv[u] = nodes[sv[u]]; nrv[u] = nodes[rv[u]]; }
#pragma unroll
    for (int u = 0; u < 4; ++u) {
        float nr = nrv[u], ns = nsv[u];
        float bs[5];
#pragma unroll
        for (int k = 0; k < 5; ++k) bs[k] = b_eb[k];
#pragma unroll
        for (int j = 0; j < 10; ++j) {
            float zl = fmaf(nr, w_pn1[j], fmaf(ns, w_pn1[10 + j], b_pn1[j]));
            float sz = selu2(zl);
#pragma unroll
            for (int k = 0; k < 5; ++k) bs[k] = fmaf(sz, W_eb[j * 5 + k], bs[k]);
        }
        float e = ev[u];
#pragma unroll
        for (int it = 0; it < 3; ++it) {
            float acc2 = b2e;
#pragma unroll
            for (int k = 0; k < 5; ++k) {
                float tt = selu2(fmaf(e, w1r0[k], bs[k]));
                acc2 = fmaf(tt, w2e[k], acc2);
            }
            e = acc2;
        }
        atomAddF(&node_acc[rv[u]], e);
    }
}

__global__ __launch_bounds__(256) void k_nodes(
        const float* __restrict__ nodes, const int* __restrict__ graph_ids,
        const float* __restrict__ fw, const float* __restrict__ node_acc,
        float* __restrict__ graph_acc) {
    float w_pe1[5], b_pe1[5], pe_w2[50], pe_b2[10], W_nb[25], b_nb[5], w1r0n[5], w2n[5];
#pragma unroll
    for (int j = 0; j < 5; ++j) w_pe1[j] = fw[96 + j];
#pragma unroll
    for (int j = 0; j < 5; ++j) b_pe1[j] = fw[101 + j];
#pragma unroll
    for (int j = 0; j < 50; ++j) pe_w2[j] = fw[106 + j];
#pragma unroll
    for (int j = 0; j < 10; ++j) pe_b2[j] = fw[156 + j];
#pragma unroll
    for (int j = 0; j < 25; ++j) W_nb[j] = fw[166 + j];
#pragma unroll
    for (int j = 0; j < 5; ++j) b_nb[j] = fw[191 + j];
#pragma unroll
    for (int j = 0; j < 5; ++j) w1r0n[j] = fw[196 + j];
#pragma unroll
    for (int j = 0; j < 5; ++j) w2n[j] = fw[201 + j];
    float b2n = fw[206];

    int i = blockIdx.x * 256 + threadIdx.x;
    bool valid = i < N_NODES_C;
    int ii = valid ? i : (N_NODES_C - 1);

    float s = node_acc[ii];
    float t5[5];
#pragma unroll
    for (int k = 0; k < 5; ++k) t5[k] = selu2(fmaf(s, w_pe1[k], b_pe1[k]));
    float he[10];
#pragma unroll
    for (int m = 0; m < 10; ++m) {
        float a = pe_b2[m];
#pragma unroll
        for (int k = 0; k < 5; ++k) a = fmaf(t5[k], pe_w2[k * 10 + m], a);
        he[m] = a;
    }
    float bs[5];
#pragma unroll
    for (int k = 0; k < 5; ++k) {
        float a = b_nb[k];
#pragma unroll
        for (int t = 0; t < 5; ++t) a = fmaf(t5[t], W_nb[t * 5 + k], a);
        bs[k] = a;
    }
    float n = nodes[ii];
#pragma unroll
    for (int it = 0; it < 3; ++it) {
        float a = b2n;
#pragma unroll
        for (int k = 0; k < 5; ++k) {
            float tt = selu2(fmaf(n, w1r0n[k], bs[k]));
            a = fmaf(tt, w2n[k], a);
        }
        n = a;
    }

    int gid = valid ? graph_ids[ii] : -1;
    if (!valid) {
        n = 0.0f;
#pragma unroll
        for (int m = 0; m < 10; ++m) he[m] = 0.0f;
    }

    int gid0 = __shfl(gid, 0, 64);
    bool allsame = __all(gid == gid0) && (gid0 >= 0);
    if (allsame) {
        float v = n;
#pragma unroll
        for (int off = 32; off > 0; off >>= 1) v += __shfl_down(v, off, 64);
        float vh[10];
#pragma unroll
        for (int m = 0; m < 10; ++m) {
            float ww = he[m];
#pragma unroll
            for (int off = 32; off > 0; off >>= 1) ww += __shfl_down(ww, off, 64);
            vh[m] = ww;
        }
        if ((threadIdx.x & 63) == 0) {
            atomAddF(&graph_acc[gid0 * 11 + 0], v);
#pragma unroll
            for (int m = 0; m < 10; ++m) atomAddF(&graph_acc[gid0 * 11 + 1 + m], vh[m]);
        }
    } else if (valid) {
        atomAddF(&graph_acc[gid * 11 + 0], n);
#pragma unroll
        for (int m = 0; m < 10; ++m) atomAddF(&graph_acc[gid * 11 + 1 + m], he[m]);
    }
}

// ---------------- launch ----------------

extern "C" void kernel_launch(void* const* d_in, const int* in_sizes, int n_in,
                              void* d_out, int out_size, void* d_ws, size_t ws_size,
                              hipStream_t stream) {
    const float* nodes     = (const float*)d_in[0];
    const float* edges     = (const float*)d_in[1];
    const int*   senders   = (const int*)d_in[2];
    const int*   receivers = (const int*)d_in[3];
    const int*   graph_ids = (const int*)d_in[4];
    const float* pn_w1 = (const float*)d_in[6];
    const float* pn_b1 = (const float*)d_in[7];
    const float* pn_w2 = (const float*)d_in[8];
    const float* pn_b2 = (const float*)d_in[9];
    const float* ue_w1 = (const float*)d_in[10];
    const float* ue_b1 = (const float*)d_in[11];
    const float* ue_w2 = (const float*)d_in[12];
    const float* ue_b2 = (const float*)d_in[13];
    const float* pe_w1 = (const float*)d_in[14];
    const float* pe_b1 = (const float*)d_in[15];
    const float* pe_w2 = (const float*)d_in[16];
    const float* pe_b2 = (const float*)d_in[17];
    const float* un_w1 = (const float*)d_in[18];
    const float* un_b1 = (const float*)d_in[19];
    const float* un_w2 = (const float*)d_in[20];
    const float* un_b2 = (const float*)d_in[21];
    const float* pr_w1 = (const float*)d_in[22];
    const float* pr_b1 = (const float*)d_in[23];
    const float* pr_w2 = (const float*)d_in[24];
    const float* pr_b2 = (const float*)d_in[25];

    float* ws        = (float*)d_ws;
    float* graph_acc = ws + GRAPH_ACC_OFF;
    float* partials  = ws + PARTIALS_OFF;
    float* fw        = ws + FW_OFF;
    float* outp      = (float*)d_out;

    if (ws_size >= (size_t)WS3_WORDS_NEEDED * 4) {
        // tier-1: split gather (2 blocks/bucket along part axis)
        int* starts_T = (int*)ws + STARTS2_OFF;
        unsigned long long* pairs64 = (unsigned long long*)((int*)ws + PAIRS64_OFF);
        float* nodeacc2 = ws + NODEACC2_OFF;

        hipLaunchKernelGGL(k_part2, dim3(NPB2), dim3(P2_TPB), 0, stream,
                           ws, edges, senders, receivers, starts_T, pairs64,
                           pn_w1, pn_b1, pn_w2, pn_b2, ue_w1, ue_b1, ue_w2, ue_b2,
                           pe_w1, pe_b1, pe_w2, pe_b2, un_w1, un_b1, un_w2, un_b2);
        hipLaunchKernelGGL(k_gather2s, dim3(2 * NBKT), dim3(1024), 0, stream,
                           nodes, fw, starts_T, pairs64, nodeacc2);
        hipLaunchKernelGGL(k_nodes2, dim3(NBKT), dim3(1024), 0, stream,
                           nodes, graph_ids, fw, nodeacc2, graph_acc, partials);
        hipLaunchKernelGGL(k_final, dim3((N_GRAPHS_C + 255) / 256), dim3(256), 0, stream,
                           graph_acc, partials, pr_w1, pr_b1, pr_w2, pr_b2, outp);
    } else if (ws_size >= (size_t)WS2_WORDS_NEEDED * 4) {
        // tier-2: r3 champion (single-item gather, fused init)
        int* starts_T = (int*)ws + STARTS2_OFF;
        unsigned long long* pairs64 = (unsigned long long*)((int*)ws + PAIRS64_OFF);

        hipLaunchKernelGGL(k_part2, dim3(NPB2), dim3(P2_TPB), 0, stream,
                           ws, edges, senders, receivers, starts_T, pairs64,
                           pn_w1, pn_b1, pn_w2, pn_b2, ue_w1, ue_b1, ue_w2, ue_b2,
                           pe_w1, pe_b1, pe_w2, pe_b2, un_w1, un_b1, un_w2, un_b2);
        hipLaunchKernelGGL(k_gather2, dim3(NBKT), dim3(1024), 0, stream,
                           nodes, graph_ids, fw, starts_T, pairs64, graph_acc, partials);
        hipLaunchKernelGGL(k_final, dim3((N_GRAPHS_C + 255) / 256), dim3(256), 0, stream,
                           graph_acc, partials, pr_w1, pr_b1, pr_w2, pr_b2, outp);
    } else {
        float* node_acc = ws + OLD_NODE_ACC_OFF;
        int len4 = OLD_ZERO_WORDS / 4;
        hipLaunchKernelGGL(k_zero, dim3((len4 + 255) / 256), dim3(256), 0, stream, ws, len4);
        hipLaunchKernelGGL(k_fuse, dim3(1), dim3(64), 0, stream,
                           pn_w1, pn_b1, pn_w2, pn_b2, ue_w1, ue_b1, ue_w2, ue_b2,
                           pe_w1, pe_b1, pe_w2, pe_b2, un_w1, un_b1, un_w2, un_b2, fw);
        hipLaunchKernelGGL(k_edges, dim3((NGROUPS_C + 255) / 256), dim3(256), 0, stream,
                           nodes, edges, senders, receivers, fw, node_acc);
        hipLaunchKernelGGL(k_nodes, dim3((N_NODES_C + 255) / 256), dim3(256), 0, stream,
                           nodes, graph_ids, fw, node_acc, graph_acc);
        hipLaunchKernelGGL(k_final, dim3((N_GRAPHS_C + 255) / 256), dim3(256), 0, stream,
                           graph_acc, partials, pr_w1, pr_b1, pr_w2, pr_b2, outp);
    }
}

// Round 10
// 282.477 us; speedup vs baseline: 2.3754x; 1.0003x over previous
//
#include <hip/hip_runtime.h>
#include <hip/hip_fp16.h>
#include <math.h>

#define N_NODES_C  500000
#define N_EDGES_C  8000000
#define N_GRAPHS_C 1000
#define NGROUPS_C  (N_EDGES_C / 4)     // 2,000,000 float4-groups

#define BSHIFT  11                     // bucket = recv >> 11
#define BWIDTH  2048
#define NBKT    245                    // ceil(500000 / 2048)

#define P2_TPB  512
#define EPB2    8192                   // edges per part-block (64KB staged u64)
#define GPB2    (EPB2 / 4)             // 2048 groups
#define NPB2    ((NGROUPS_C + GPB2 - 1) / GPB2) // 977
#define SROW2   992
#define RITER2  (GPB2 / P2_TPB)        // 4
#define HALF_P  489                    // parts per half (h=0: 489, h=1: 488)
#define TBLCAP  1024                   // chunk table entries (covers M<=32768)

// ---- workspace layout (32-bit word offsets) ----
#define GRAPH_ACC_OFF 0                          // 11000 floats
#define PARTIALS_OFF  11008                      // 2*11000 floats
#define FW_OFF        33024                      // 207 floats fused weights
#define ZERO_HEAD     33024                      // graph_acc + partials

#define STARTS2_OFF   33280                      // 246 * SROW2 ints
#define PAIRS64_OFF   (STARTS2_OFF + 246 * SROW2)        // 277312; *4%16==0
#define WS2_WORDS_NEEDED (PAIRS64_OFF + NPB2 * EPB2 * 2) // 16,284,480 (65.1MB)

// tier-1 extra: two partial node-acc halves (plain stores, no atomics)
#define NA2_STRIDE    (NBKT * BWIDTH)                    // 501,760 floats/half
#define NODEACC2_OFF  WS2_WORDS_NEEDED                   // 16,284,480
#define WS3_WORDS_NEEDED (NODEACC2_OFF + 2 * NA2_STRIDE) // 17,288,000 (69.15MB)

// fallback layout
#define OLD_NODE_ACC_OFF 33536
#define OLD_ZERO_WORDS   (OLD_NODE_ACC_OFF + N_NODES_C)

#define LOG2E_F 1.4426950408889634f

// fused-weight layout inside fw[]; (L) = pre-scaled by log2(e):
// 0:w_pn1[20](L) 20:b_pn1[10](L) 30:W_eb[50](L) 80:b_eb[5](L) 85:w1r0_e[5](L)
// 90:w2_e[5] 95:b2_e
// 96:w_pe1[5](L) 101:b_pe1[5](L) 106:pe_w2[50] 156:pe_b2[10]
// 166:W_nb[25](L) 191:b_nb[5](L) 196:w1r0_n[5](L) 201:w2_n[5] 206:b2_n

__device__ __forceinline__ float selu2(float xl) {
    const float C1 = 0.7282901039f;        // 1.0507009873554805 * ln(2)
    const float C2 = 1.7580993408473766f;  // scale * alpha
    float e = __builtin_amdgcn_exp2f(xl);
    float neg = fmaf(C2, e, -C2);
    return xl > 0.0f ? C1 * xl : neg;
}

__device__ __forceinline__ float selu_f(float x) {
    const float scale = 1.0507009873554805f;
    const float sa    = 1.0507009873554805f * 1.6732632423543772f;
    float neg = sa * (__expf(x) - 1.0f);
    return x > 0.0f ? scale * x : neg;
}

__device__ __forceinline__ void atomAddF(float* p, float v) {
    __hip_atomic_fetch_add(p, v, __ATOMIC_RELAXED, __HIP_MEMORY_SCOPE_AGENT);
}

__device__ __forceinline__ void fuse_weights(
        int t,
        const float* __restrict__ pn_w1, const float* __restrict__ pn_b1,
        const float* __restrict__ pn_w2, const float* __restrict__ pn_b2,
        const float* __restrict__ ue_w1, const float* __restrict__ ue_b1,
        const float* __restrict__ ue_w2, const float* __restrict__ ue_b2,
        const float* __restrict__ pe_w1, const float* __restrict__ pe_b1,
        const float* __restrict__ pe_w2, const float* __restrict__ pe_b2,
        const float* __restrict__ un_w1, const float* __restrict__ un_b1,
        const float* __restrict__ un_w2, const float* __restrict__ un_b2,
        float* __restrict__ fw) {
    const float L = LOG2E_F;
    if (t < 20) fw[0 + t] = pn_w1[t] * L;
    if (t < 10) fw[20 + t] = pn_b1[t] * L;
    if (t < 50) {
        int j = t / 5, k = t % 5;
        float s = 0.0f;
        for (int m = 0; m < 10; ++m) s += pn_w2[j * 10 + m] * ue_w1[(1 + m) * 5 + k];
        fw[30 + t] = s * L;
    }
    if (t < 5) {
        float s = ue_b1[t];
        for (int m = 0; m < 10; ++m) s += pn_b2[m] * ue_w1[(1 + m) * 5 + t];
        fw[80 + t] = s * L;
    }
    if (t < 5)  fw[85 + t]  = ue_w1[t] * L;
    if (t < 5)  fw[90 + t]  = ue_w2[t];
    if (t == 0) fw[95]      = ue_b2[0];
    if (t < 5)  fw[96 + t]  = pe_w1[t] * L;
    if (t < 5)  fw[101 + t] = pe_b1[t] * L;
    if (t < 50) fw[106 + t] = pe_w2[t];
    if (t < 10) fw[156 + t] = pe_b2[t];
    if (t < 25) {
        int j = t / 5, k = t % 5;
        float s = 0.0f;
        for (int m = 0; m < 10; ++m) s += pe_w2[j * 10 + m] * un_w1[(1 + m) * 5 + k];
        fw[166 + t] = s * L;
    }
    if (t < 5) {
        float s = un_b1[t];
        for (int m = 0; m < 10; ++m) s += pe_b2[m] * un_w1[(1 + m) * 5 + t];
        fw[191 + t] = s * L;
    }
    if (t < 5)  fw[196 + t] = un_w1[t] * L;
    if (t < 5)  fw[201 + t] = un_w2[t];
    if (t == 0) fw[206]     = un_b2[0];
}

__global__ void k_fuse(const float* pn_w1, const float* pn_b1, const float* pn_w2, const float* pn_b2,
                       const float* ue_w1, const float* ue_b1, const float* ue_w2, const float* ue_b2,
                       const float* pe_w1, const float* pe_b1, const float* pe_w2, const float* pe_b2,
                       const float* un_w1, const float* un_b1, const float* un_w2, const float* un_b2,
                       float* fw) {
    fuse_weights(threadIdx.x, pn_w1, pn_b1, pn_w2, pn_b2, ue_w1, ue_b1, ue_w2, ue_b2,
                 pe_w1, pe_b1, pe_w2, pe_b2, un_w1, un_b1, un_w2, un_b2, fw);
}

__global__ void k_final(const float* __restrict__ graph_acc,
                        const float* __restrict__ partials,
                        const float* __restrict__ pr_w1, const float* __restrict__ pr_b1,
                        const float* __restrict__ pr_w2, const float* __restrict__ pr_b2,
                        float* __restrict__ out) {
    int g = blockIdx.x * blockDim.x + threadIdx.x;
    if (g >= N_GRAPHS_C) return;
    float gv[11];
#pragma unroll
    for (int f = 0; f < 11; ++f)
        gv[f] = graph_acc[g * 11 + f] + partials[g * 11 + f] + partials[11000 + g * 11 + f];
    float h[10];
#pragma unroll
    for (int j = 0; j < 10; ++j) {
        float z = pr_b1[j];
#pragma unroll
        for (int f = 0; f < 11; ++f) z = fmaf(gv[f], pr_w1[f * 10 + j], z);
        h[j] = selu_f(z);
    }
    float o[10];
    float mx = -1e30f;
#pragma unroll
    for (int j = 0; j < 10; ++j) {
        float z = pr_b2[j];
#pragma unroll
        for (int m = 0; m < 10; ++m) z = fmaf(h[m], pr_w2[m * 10 + j], z);
        o[j] = z;
        mx = fmaxf(mx, z);
    }
    float sum = 0.0f;
#pragma unroll
    for (int j = 0; j < 10; ++j) { o[j] = __expf(o[j] - mx); sum += o[j]; }
    float inv = 1.0f / sum;
#pragma unroll
    for (int j = 0; j < 10; ++j) out[g * 10 + j] = o[j] * inv;
}

// ==================== main path: sort-first, MLP-in-gather ====================

// k_part2: streaming counting sort ONLY (no MLP, no node gathers).
// Packs u64 {recv_local:11 @bit51 | sender:19 @bit32 | edge f32 @bit0}.
// Fused init: each block zeros a 34-word slice of graph_acc/partials;
// block 0 additionally builds the fused weights (consumed next kernel).
__global__ __launch_bounds__(P2_TPB) void k_part2(
        float* __restrict__ ws,
        const float* __restrict__ edges,
        const int* __restrict__ senders, const int* __restrict__ receivers,
        int* __restrict__ starts_T, unsigned long long* __restrict__ pairs64,
        const float* pn_w1, const float* pn_b1, const float* pn_w2, const float* pn_b2,
        const float* ue_w1, const float* ue_b1, const float* ue_w2, const float* ue_b2,
        const float* pe_w1, const float* pe_b1, const float* pe_w2, const float* pe_b2,
        const float* un_w1, const float* un_b1, const float* un_w2, const float* un_b2) {
    __shared__ int hist[256];
    __shared__ int cursorS[256];
    __shared__ alignas(16) unsigned long long staged[EPB2];   // 64 KB

    int tid = threadIdx.x;
    int p   = blockIdx.x;

    // fused init
    if (tid < 34) {
        int z = p * 34 + tid;
        if (z < ZERO_HEAD) ws[z] = 0.0f;
    }
    if (p == 0)
        fuse_weights(tid, pn_w1, pn_b1, pn_w2, pn_b2, ue_w1, ue_b1, ue_w2, ue_b2,
                     pe_w1, pe_b1, pe_w2, pe_b2, un_w1, un_b1, un_w2, un_b2, ws + FW_OFF);

    int gstart = p * GPB2;
    int gnum   = NGROUPS_C - gstart;
    if (gnum > GPB2) gnum = GPB2;

    if (tid < 256) hist[tid] = 0;
    __syncthreads();

    // phase A: load receivers (kept in regs), histogram
    int4 rv4[RITER2];
#pragma unroll
    for (int r = 0; r < RITER2; ++r) {
        int idx = r * P2_TPB + tid;
        int gi  = gstart + (idx < gnum ? idx : 0);
        rv4[r] = ((const int4*)receivers)[gi];
        if (idx < gnum) {
            atomicAdd(&hist[rv4[r].x >> BSHIFT], 1);
            atomicAdd(&hist[rv4[r].y >> BSHIFT], 1);
            atomicAdd(&hist[rv4[r].z >> BSHIFT], 1);
            atomicAdd(&hist[rv4[r].w >> BSHIFT], 1);
        }
    }
    __syncthreads();

    // inclusive scan over 256 buckets (tids 0..255 active)
    int orig = 0, val = 0;
    if (tid < 256) { orig = hist[tid]; val = orig; }
    for (int d = 1; d < 256; d <<= 1) {
        int add = 0;
        if (tid >= d && tid < 256) add = hist[tid - d];
        __syncthreads();
        if (tid >= d && tid < 256) { val += add; hist[tid] = val; }
        __syncthreads();
    }
    int excl = val - orig;
    if (tid < 256) cursorS[tid] = excl;
    if (tid < 246) starts_T[tid * SROW2 + p] = excl;
    __syncthreads();

    // phase C: pack + counting sort into LDS
#pragma unroll
    for (int r = 0; r < RITER2; ++r) {
        int idx = r * P2_TPB + tid;
        int gi  = gstart + (idx < gnum ? idx : 0);
        float4 e4 = ((const float4*)edges)[gi];
        int4   s4 = ((const int4*)senders)[gi];
        int4   rv = rv4[r];
        if (idx < gnum) {
            int   rvv[4] = {rv.x, rv.y, rv.z, rv.w};
            int   svv[4] = {s4.x, s4.y, s4.z, s4.w};
            float evv[4] = {e4.x, e4.y, e4.z, e4.w};
#pragma unroll
            for (int u = 0; u < 4; ++u) {
                int bkt  = rvv[u] >> BSHIFT;
                int slot = atomicAdd(&cursorS[bkt], 1);
                unsigned long long pk =
                    ((unsigned long long)(rvv[u] & (BWIDTH - 1)) << 51)
                  | ((unsigned long long)(unsigned)svv[u] << 32)
                  | (unsigned long long)__float_as_uint(evv[u]);
                staged[slot] = pk;
            }
        }
    }
    __syncthreads();

    // flush: contiguous uint4 stores (gnum*4 u64 = gnum*2 uint4)
    const uint4* st4 = (const uint4*)staged;
    uint4* dst = (uint4*)(pairs64 + (size_t)p * EPB2);
    int n4 = gnum * 2;
    for (int i = tid; i < n4; i += P2_TPB) dst[i] = st4[i];
}

// shared edge-MLP body (single-item, r3-proven form)
#define EDGE_MLP_BODY(pk, accf)                                              \
    {                                                                        \
        int   rl   = (int)((pk) >> 51);                                      \
        int   sidx = (int)(((pk) >> 32) & 0x7FFFFULL);                       \
        float e    = __uint_as_float((unsigned)(pk));                        \
        float nr   = nf[rl];                                                 \
        float ns   = nodes[sidx];                                            \
        float bs[5];                                                         \
        _Pragma("unroll")                                                    \
        for (int k = 0; k < 5; ++k) bs[k] = b_eb[k];                         \
        _Pragma("unroll")                                                    \
        for (int j = 0; j < 10; ++j) {                                       \
            float zl = fmaf(nr, w_pn1[j], fmaf(ns, w_pn1[10 + j], b_pn1[j]));\
            float sz = selu2(zl);                                            \
            _Pragma("unroll")                                                \
            for (int k = 0; k < 5; ++k) bs[k] = fmaf(sz, W_eb[j*5+k], bs[k]);\
        }                                                                    \
        _Pragma("unroll")                                                    \
        for (int it = 0; it < 3; ++it) {                                     \
            float acc2 = b2e;                                                \
            _Pragma("unroll")                                                \
            for (int k = 0; k < 5; ++k) {                                    \
                float tt = selu2(fmaf(e, w1r0[k], bs[k]));                   \
                acc2 = fmaf(tt, w2e[k], acc2);                               \
            }                                                                \
            e = acc2;                                                        \
        }                                                                    \
        atomicAdd(&(accf)[rl], e);                                           \
    }

// k_gather2s (tier-1): TWO blocks per bucket, split along the PART axis.
// Per-edge segment lookup via a per-32-edge CHUNK TABLE (built once with
// 1024 parallel 9-step searches) + a short advance loop — replaces the
// per-edge 9-step dependent-LDS binary search (~45 VALU + 9 serial LDS
// reads/edge) with ~1 LDS read + ~0.5 advances.
__global__ __launch_bounds__(1024, 8) void k_gather2s(
        const float* __restrict__ nodes,
        const float* __restrict__ fw, const int* __restrict__ starts_T,
        const unsigned long long* __restrict__ pairs64,
        float* __restrict__ nodeacc2) {
    __shared__ float accf[BWIDTH];        // 8 KB
    __shared__ float nf[BWIDTH];          // 8 KB
    __shared__ int   s0[HALF_P];          // 1.9 KB
    __shared__ int   pst[HALF_P + 1];     // 1.9 KB
    __shared__ int   sc[512];             // 2 KB
    __shared__ unsigned short tbl[TBLCAP];// 2 KB chunk->segment table
    int tid = threadIdx.x;
    int b   = blockIdx.x >> 1;
    int h   = blockIdx.x & 1;
    int pbase  = h * HALF_P;
    int pcount = h ? (NPB2 - HALF_P) : HALF_P;   // 488 or 489

    int nodeBase = b << BSHIFT;
    int lastIdx  = nodeBase + BWIDTH;
    if (lastIdx > N_NODES_C) lastIdx = N_NODES_C;
    int lim = lastIdx - nodeBase;

    accf[tid] = 0.0f; accf[1024 + tid] = 0.0f;
    nf[tid]        = (tid        < lim) ? nodes[nodeBase + tid]        : 0.0f;
    nf[1024 + tid] = (1024 + tid < lim) ? nodes[nodeBase + 1024 + tid] : 0.0f;

    int cntv = 0;
    if (tid < pcount) {
        int a = starts_T[b * SROW2 + pbase + tid];
        int c = starts_T[(b + 1) * SROW2 + pbase + tid];
        s0[tid] = a;
        cntv = c - a;
    }
    if (tid < 512) sc[tid] = cntv;
    __syncthreads();

    // inclusive scan over 512 (pcount real + zero pad), threads 0..511
    int v = cntv;
    for (int d = 1; d < 512; d <<= 1) {
        int add = (tid >= d && tid < 512) ? sc[tid - d] : 0;
        __syncthreads();
        if (tid >= d && tid < 512) { v += add; sc[tid] = v; }
        __syncthreads();
    }
    if (tid == 0) pst[0] = 0;
    if (tid < pcount) pst[tid + 1] = v;
    __syncthreads();

    int M = pst[pcount];   // edges for this bucket-half (~16.4K expected)

    // build chunk table: tbl[c] = segment containing edge index c*32
    {
        int nch = (M + 31) >> 5;
        if (nch > TBLCAP) nch = TBLCAP;
        for (int c = tid; c < nch; c += 1024) {
            int target = c << 5;
            int lo = 0, hi = pcount;
#pragma unroll
            for (int s = 0; s < 9; ++s) {
                int mid = (lo + hi) >> 1;
                if (pst[mid] <= target) lo = mid; else hi = mid;
            }
            tbl[c] = (unsigned short)lo;
        }
    }
    __syncthreads();

    {
        float w_pn1[20], b_pn1[10], W_eb[50], b_eb[5], w1r0[5], w2e[5];
#pragma unroll
        for (int j = 0; j < 20; ++j) w_pn1[j] = fw[j];
#pragma unroll
        for (int j = 0; j < 10; ++j) b_pn1[j] = fw[20 + j];
#pragma unroll
        for (int j = 0; j < 50; ++j) W_eb[j] = fw[30 + j];
#pragma unroll
        for (int j = 0; j < 5; ++j) b_eb[j] = fw[80 + j];
#pragma unroll
        for (int j = 0; j < 5; ++j) w1r0[j] = fw[85 + j];
#pragma unroll
        for (int j = 0; j < 5; ++j) w2e[j] = fw[90 + j];
        float b2e = fw[95];

#pragma unroll 1
        for (int i = tid; i < M; i += 1024) {
            int c = i >> 5;
            int lo;
            if (c < TBLCAP) {
                lo = tbl[c];
                while (pst[lo + 1] <= i) ++lo;   // ~0-1 advances (seg ~34)
            } else {
                int hi = pcount; lo = 0;
#pragma unroll
                for (int s = 0; s < 9; ++s) {
                    int mid = (lo + hi) >> 1;
                    if (pst[mid] <= i) lo = mid; else hi = mid;
                }
            }
            unsigned long long pk =
                pairs64[(size_t)(pbase + lo) * EPB2 + s0[lo] + (i - pst[lo])];
            EDGE_MLP_BODY(pk, accf)
        }
    }
    __syncthreads();

    // flush partial accf (coalesced plain stores; no atomics)
    float* dst = nodeacc2 + (size_t)h * NA2_STRIDE + (size_t)b * BWIDTH;
    dst[tid] = accf[tid];
    dst[1024 + tid] = accf[1024 + tid];
}

// k_nodes2 (tier-1): sum the two partial halves, node MLP + graph reduction
// with parity-partials (proven epilogue; one block per bucket).
__global__ __launch_bounds__(1024) void k_nodes2(
        const float* __restrict__ nodes, const int* __restrict__ graph_ids,
        const float* __restrict__ fw, const float* __restrict__ nodeacc2,
        float* __restrict__ graph_acc, float* __restrict__ partials) {
    __shared__ float garr[32 * 11];
    int tid = threadIdx.x;
    int b   = blockIdx.x;

    if (tid < 352) garr[tid] = 0.0f;

    float w_pe1[5], b_pe1[5], pe_w2[50], pe_b2[10], W_nb[25], b_nb[5], w1r0n[5], w2n[5];
#pragma unroll
    for (int j = 0; j < 5; ++j) w_pe1[j] = fw[96 + j];
#pragma unroll
    for (int j = 0; j < 5; ++j) b_pe1[j] = fw[101 + j];
#pragma unroll
    for (int j = 0; j < 50; ++j) pe_w2[j] = fw[106 + j];
#pragma unroll
    for (int j = 0; j < 10; ++j) pe_b2[j] = fw[156 + j];
#pragma unroll
    for (int j = 0; j < 25; ++j) W_nb[j] = fw[166 + j];
#pragma unroll
    for (int j = 0; j < 5; ++j) b_nb[j] = fw[191 + j];
#pragma unroll
    for (int j = 0; j < 5; ++j) w1r0n[j] = fw[196 + j];
#pragma unroll
    for (int j = 0; j < 5; ++j) w2n[j] = fw[201 + j];
    float b2n = fw[206];

    int nodeBase = b << BSHIFT;
    int lastIdx  = nodeBase + BWIDTH;
    if (lastIdx > N_NODES_C) lastIdx = N_NODES_C;
    int gidBase = graph_ids[nodeBase];
    int gidEnd  = graph_ids[lastIdx - 1];
    __syncthreads();

#pragma unroll
    for (int q = 0; q < 2; ++q) {
        int local = q * 1024 + tid;
        int i = nodeBase + local;
        bool valid = i < N_NODES_C;

        float s = nodeacc2[(size_t)b * BWIDTH + local]
                + nodeacc2[(size_t)NA2_STRIDE + (size_t)b * BWIDTH + local];
        float t5[5];
#pragma unroll
        for (int k = 0; k < 5; ++k) t5[k] = selu2(fmaf(s, w_pe1[k], b_pe1[k]));
        float he[10];
#pragma unroll
        for (int m = 0; m < 10; ++m) {
            float a = pe_b2[m];
#pragma unroll
            for (int k = 0; k < 5; ++k) a = fmaf(t5[k], pe_w2[k * 10 + m], a);
            he[m] = a;
        }
        float bs[5];
#pragma unroll
        for (int k = 0; k < 5; ++k) {
            float a = b_nb[k];
#pragma unroll
            for (int t = 0; t < 5; ++t) a = fmaf(t5[t], W_nb[t * 5 + k], a);
            bs[k] = a;
        }
        float n = valid ? nodes[i] : 0.0f;
#pragma unroll
        for (int it = 0; it < 3; ++it) {
            float a = b2n;
#pragma unroll
            for (int k = 0; k < 5; ++k) {
                float tt = selu2(fmaf(n, w1r0n[k], bs[k]));
                a = fmaf(tt, w2n[k], a);
            }
            n = a;
        }

        int gid = valid ? graph_ids[i] : -1;
        if (!valid) {
            n = 0.0f;
#pragma unroll
            for (int m = 0; m < 10; ++m) he[m] = 0.0f;
        }

        int gid0 = __shfl(gid, 0, 64);
        bool allsame = __all(gid == gid0) && (gid0 >= 0);
        if (allsame) {
            float vv = n;
#pragma unroll
            for (int off = 32; off > 0; off >>= 1) vv += __shfl_down(vv, off, 64);
            float vh[10];
#pragma unroll
            for (int m = 0; m < 10; ++m) {
                float ww = he[m];
#pragma unroll
                for (int off = 32; off > 0; off >>= 1) ww += __shfl_down(ww, off, 64);
                vh[m] = ww;
            }
            if ((tid & 63) == 0) {
                int off = gid0 - gidBase;
                if (off >= 0 && off < 32) {
                    atomicAdd(&garr[off * 11 + 0], vv);
#pragma unroll
                    for (int m = 0; m < 10; ++m) atomicAdd(&garr[off * 11 + 1 + m], vh[m]);
                } else {
                    atomAddF(&graph_acc[gid0 * 11 + 0], vv);
#pragma unroll
                    for (int m = 0; m < 10; ++m) atomAddF(&graph_acc[gid0 * 11 + 1 + m], vh[m]);
                }
            }
        } else if (valid) {
            int off = gid - gidBase;
            if (off >= 0 && off < 32) {
                atomicAdd(&garr[off * 11 + 0], n);
#pragma unroll
                for (int m = 0; m < 10; ++m) atomicAdd(&garr[off * 11 + 1 + m], he[m]);
            } else {
                atomAddF(&graph_acc[gid * 11 + 0], n);
#pragma unroll
                for (int m = 0; m < 10; ++m) atomAddF(&graph_acc[gid * 11 + 1 + m], he[m]);
            }
        }
    }
    __syncthreads();

    int ngl = gidEnd - gidBase + 1;
    if (ngl > 32) ngl = 32;
    int par = (b & 1) * 11000;
    for (int t = tid; t < ngl * 11; t += 1024) {
        int off = t / 11, f = t - off * 11;
        partials[par + (gidBase + off) * 11 + f] = garr[t];
    }
}

// k_gather2 (tier-2): exact r3-proven kernel — single-item loop, VGPR 32.
__global__ __launch_bounds__(1024) void k_gather2(
        const float* __restrict__ nodes, const int* __restrict__ graph_ids,
        const float* __restrict__ fw, const int* __restrict__ starts_T,
        const unsigned long long* __restrict__ pairs64,
        float* __restrict__ graph_acc, float* __restrict__ partials) {
    __shared__ float accf[BWIDTH];
    __shared__ float nf[BWIDTH];
    __shared__ int   s0[NPB2];
    __shared__ int   pst[NPB2 + 1];
    __shared__ int   sc[1024];
    __shared__ float garr[32 * 11];
    int tid = threadIdx.x;
    int b   = blockIdx.x;

    int nodeBase = b << BSHIFT;
    int lastIdx  = nodeBase + BWIDTH;
    if (lastIdx > N_NODES_C) lastIdx = N_NODES_C;
    int lim = lastIdx - nodeBase;

    accf[tid] = 0.0f; accf[1024 + tid] = 0.0f;
    nf[tid]        = (tid        < lim) ? nodes[nodeBase + tid]        : 0.0f;
    nf[1024 + tid] = (1024 + tid < lim) ? nodes[nodeBase + 1024 + tid] : 0.0f;
    if (tid < 352) garr[tid] = 0.0f;

    int cntv = 0;
    if (tid < NPB2) {
        int a = starts_T[b * SROW2 + tid];
        int c = starts_T[(b + 1) * SROW2 + tid];
        s0[tid] = a;
        cntv = c - a;
    }
    sc[tid] = cntv;
    __syncthreads();

    int v = cntv;
    for (int d = 1; d < 1024; d <<= 1) {
        int add = (tid >= d) ? sc[tid - d] : 0;
        __syncthreads();
        if (tid >= d) { v += add; sc[tid] = v; }
        __syncthreads();
    }
    if (tid == 0) pst[0] = 0;
    if (tid < NPB2) pst[tid + 1] = v;
    __syncthreads();

    int M = pst[NPB2];

    {
        float w_pn1[20], b_pn1[10], W_eb[50], b_eb[5], w1r0[5], w2e[5];
#pragma unroll
        for (int j = 0; j < 20; ++j) w_pn1[j] = fw[j];
#pragma unroll
        for (int j = 0; j < 10; ++j) b_pn1[j] = fw[20 + j];
#pragma unroll
        for (int j = 0; j < 50; ++j) W_eb[j] = fw[30 + j];
#pragma unroll
        for (int j = 0; j < 5; ++j) b_eb[j] = fw[80 + j];
#pragma unroll
        for (int j = 0; j < 5; ++j) w1r0[j] = fw[85 + j];
#pragma unroll
        for (int j = 0; j < 5; ++j) w2e[j] = fw[90 + j];
        float b2e = fw[95];

#pragma unroll 1
        for (int i = tid; i < M; i += 1024) {
            int lo = 0, hi = NPB2;
#pragma unroll
            for (int s = 0; s < 10; ++s) {
                int mid = (lo + hi) >> 1;
                if (pst[mid] <= i) lo = mid; else hi = mid;
            }
            unsigned long long pk =
                pairs64[(size_t)lo * EPB2 + s0[lo] + (i - pst[lo])];
            EDGE_MLP_BODY(pk, accf)
        }
    }
    __syncthreads();

    float w_pe1[5], b_pe1[5], pe_w2[50], pe_b2[10], W_nb[25], b_nb[5], w1r0n[5], w2n[5];
#pragma unroll
    for (int j = 0; j < 5; ++j) w_pe1[j] = fw[96 + j];
#pragma unroll
    for (int j = 0; j < 5; ++j) b_pe1[j] = fw[101 + j];
#pragma unroll
    for (int j = 0; j < 50; ++j) pe_w2[j] = fw[106 + j];
#pragma unroll
    for (int j = 0; j < 10; ++j) pe_b2[j] = fw[156 + j];
#pragma unroll
    for (int j = 0; j < 25; ++j) W_nb[j] = fw[166 + j];
#pragma unroll
    for (int j = 0; j < 5; ++j) b_nb[j] = fw[191 + j];
#pragma unroll
    for (int j = 0; j < 5; ++j) w1r0n[j] = fw[196 + j];
#pragma unroll
    for (int j = 0; j < 5; ++j) w2n[j] = fw[201 + j];
    float b2n = fw[206];

    int gidBase = graph_ids[nodeBase];
    int gidEnd  = graph_ids[lastIdx - 1];

#pragma unroll
    for (int q = 0; q < 2; ++q) {
        int local = q * 1024 + tid;
        int i = nodeBase + local;
        bool valid = i < N_NODES_C;

        float s = accf[local];
        float t5[5];
#pragma unroll
        for (int k = 0; k < 5; ++k) t5[k] = selu2(fmaf(s, w_pe1[k], b_pe1[k]));
        float he[10];
#pragma unroll
        for (int m = 0; m < 10; ++m) {
            float a = pe_b2[m];
#pragma unroll
            for (int k = 0; k < 5; ++k) a = fmaf(t5[k], pe_w2[k * 10 + m], a);
            he[m] = a;
        }
        float bs[5];
#pragma unroll
        for (int k = 0; k < 5; ++k) {
            float a = b_nb[k];
#pragma unroll
            for (int t = 0; t < 5; ++t) a = fmaf(t5[t], W_nb[t * 5 + k], a);
            bs[k] = a;
        }
        float n = valid ? nf[local] : 0.0f;
#pragma unroll
        for (int it = 0; it < 3; ++it) {
            float a = b2n;
#pragma unroll
            for (int k = 0; k < 5; ++k) {
                float tt = selu2(fmaf(n, w1r0n[k], bs[k]));
                a = fmaf(tt, w2n[k], a);
            }
            n = a;
        }

        int gid = valid ? graph_ids[i] : -1;
        if (!valid) {
            n = 0.0f;
#pragma unroll
            for (int m = 0; m < 10; ++m) he[m] = 0.0f;
        }

        int gid0 = __shfl(gid, 0, 64);
        bool allsame = __all(gid == gid0) && (gid0 >= 0);
        if (allsame) {
            float vv = n;
#pragma unroll
            for (int off = 32; off > 0; off >>= 1) vv += __shfl_down(vv, off, 64);
            float vh[10];
#pragma unroll
            for (int m = 0; m < 10; ++m) {
                float ww = he[m];
#pragma unroll
                for (int off = 32; off > 0; off >>= 1) ww += __shfl_down(ww, off, 64);
                vh[m] = ww;
            }
            if ((tid & 63) == 0) {
                int off = gid0 - gidBase;
                if (off >= 0 && off < 32) {
                    atomicAdd(&garr[off * 11 + 0], vv);
#pragma unroll
                    for (int m = 0; m < 10; ++m) atomicAdd(&garr[off * 11 + 1 + m], vh[m]);
                } else {
                    atomAddF(&graph_acc[gid0 * 11 + 0], vv);
#pragma unroll
                    for (int m = 0; m < 10; ++m) atomAddF(&graph_acc[gid0 * 11 + 1 + m], vh[m]);
                }
            }
        } else if (valid) {
            int off = gid - gidBase;
            if (off >= 0 && off < 32) {
                atomicAdd(&garr[off * 11 + 0], n);
#pragma unroll
                for (int m = 0; m < 10; ++m) atomicAdd(&garr[off * 11 + 1 + m], he[m]);
            } else {
                atomAddF(&graph_acc[gid * 11 + 0], n);
#pragma unroll
                for (int m = 0; m < 10; ++m) atomAddF(&graph_acc[gid * 11 + 1 + m], he[m]);
            }
        }
    }
    __syncthreads();

    int ngl = gidEnd - gidBase + 1;
    if (ngl > 32) ngl = 32;
    int par = (b & 1) * 11000;
    for (int t = tid; t < ngl * 11; t += 1024) {
        int off = t / 11, f = t - off * 11;
        partials[par + (gidBase + off) * 11 + f] = garr[t];
    }
}

// ---------------- fallback path (ws too small) ----------------

__global__ __launch_bounds__(256) void k_zero(float* __restrict__ ws, int len4) {
    int i = blockIdx.x * 256 + threadIdx.x;
    if (i < len4) ((float4*)ws)[i] = make_float4(0.f, 0.f, 0.f, 0.f);
}

__global__ __launch_bounds__(256) void k_edges(
        const float* __restrict__ nodes, const float* __restrict__ edges,
        const int* __restrict__ senders, const int* __restrict__ receivers,
        const float* __restrict__ fw, float* __restrict__ node_acc) {
    float w_pn1[20], b_pn1[10], W_eb[50], b_eb[5], w1r0[5], w2e[5];
#pragma unroll
    for (int j = 0; j < 20; ++j) w_pn1[j] = fw[j];
#pragma unroll
    for (int j = 0; j < 10; ++j) b_pn1[j] = fw[20 + j];
#pragma unroll
    for (int j = 0; j < 50; ++j) W_eb[j] = fw[30 + j];
#pragma unroll
    for (int j = 0; j < 5; ++j) b_eb[j] = fw[80 + j];
#pragma unroll
    for (int j = 0; j < 5; ++j) w1r0[j] = fw[85 + j];
#pragma unroll
    for (int j = 0; j < 5; ++j) w2e[j] = fw[90 + j];
    float b2e = fw[95];

    int g = blockIdx.x * 256 + threadIdx.x;
    if (g >= NGROUPS_C) return;

    float4 e4 = ((const float4*)edges)[g];
    int4  s4 = ((const int4*)senders)[g];
    int4  r4 = ((const int4*)receivers)[g];
    float ev[4] = {e4.x, e4.y, e4.z, e4.w};
    int   sv[4] = {s4.x, s4.y, s4.z, s4.w};
    int   rv[4] = {r4.x, r4.y, r4.z, r4.w};
    float nsv[4], nrv[4];
#pragma unroll
    for (int u = 0; u < 4; ++u) { nsv[u] = nodes[sv[u]]; nrv[u] = nodes[rv[u]]; }
#pragma unroll
    for (int u = 0; u < 4; ++u) {
        float nr = nrv[u], ns = nsv[u];
        float bs[5];
#pragma unroll
        for (int k = 0; k < 5; ++k) bs[k] = b_eb[k];
#pragma unroll
        for (int j = 0; j < 10; ++j) {
            float zl = fmaf(nr, w_pn1[j], fmaf(ns, w_pn1[10 + j], b_pn1[j]));
            float sz = selu2(zl);
#pragma unroll
            for (int k = 0; k < 5; ++k) bs[k] = fmaf(sz, W_eb[j * 5 + k], bs[k]);
        }
        float e = ev[u];
#pragma unroll
        for (int it = 0; it < 3; ++it) {
            float acc2 = b2e;
#pragma unroll
            for (int k = 0; k < 5; ++k) {
                float tt = selu2(fmaf(e, w1r0[k], bs[k]));
                acc2 = fmaf(tt, w2e[k], acc2);
            }
            e = acc2;
        }
        atomAddF(&node_acc[rv[u]], e);
    }
}

__global__ __launch_bounds__(256) void k_nodes(
        const float* __restrict__ nodes, const int* __restrict__ graph_ids,
        const float* __restrict__ fw, const float* __restrict__ node_acc,
        float* __restrict__ graph_acc) {
    float w_pe1[5], b_pe1[5], pe_w2[50], pe_b2[10], W_nb[25], b_nb[5], w1r0n[5], w2n[5];
#pragma unroll
    for (int j = 0; j < 5; ++j) w_pe1[j] = fw[96 + j];
#pragma unroll
    for (int j = 0; j < 5; ++j) b_pe1[j] = fw[101 + j];
#pragma unroll
    for (int j = 0; j < 50; ++j) pe_w2[j] = fw[106 + j];
#pragma unroll
    for (int j = 0; j < 10; ++j) pe_b2[j] = fw[156 + j];
#pragma unroll
    for (int j = 0; j < 25; ++j) W_nb[j] = fw[166 + j];
#pragma unroll
    for (int j = 0; j < 5; ++j) b_nb[j] = fw[191 + j];
#pragma unroll
    for (int j = 0; j < 5; ++j) w1r0n[j] = fw[196 + j];
#pragma unroll
    for (int j = 0; j < 5; ++j) w2n[j] = fw[201 + j];
    float b2n = fw[206];

    int i = blockIdx.x * 256 + threadIdx.x;
    bool valid = i < N_NODES_C;
    int ii = valid ? i : (N_NODES_C - 1);

    float s = node_acc[ii];
    float t5[5];
#pragma unroll
    for (int k = 0; k < 5; ++k) t5[k] = selu2(fmaf(s, w_pe1[k], b_pe1[k]));
    float he[10];
#pragma unroll
    for (int m = 0; m < 10; ++m) {
        float a = pe_b2[m];
#pragma unroll
        for (int k = 0; k < 5; ++k) a = fmaf(t5[k], pe_w2[k * 10 + m], a);
        he[m] = a;
    }
    float bs[5];
#pragma unroll
    for (int k = 0; k < 5; ++k) {
        float a = b_nb[k];
#pragma unroll
        for (int t = 0; t < 5; ++t) a = fmaf(t5[t], W_nb[t * 5 + k], a);
        bs[k] = a;
    }
    float n = nodes[ii];
#pragma unroll
    for (int it = 0; it < 3; ++it) {
        float a = b2n;
#pragma unroll
        for (int k = 0; k < 5; ++k) {
            float tt = selu2(fmaf(n, w1r0n[k], bs[k]));
            a = fmaf(tt, w2n[k], a);
        }
        n = a;
    }

    int gid = valid ? graph_ids[ii] : -1;
    if (!valid) {
        n = 0.0f;
#pragma unroll
        for (int m = 0; m < 10; ++m) he[m] = 0.0f;
    }

    int gid0 = __shfl(gid, 0, 64);
    bool allsame = __all(gid == gid0) && (gid0 >= 0);
    if (allsame) {
        float v = n;
#pragma unroll
        for (int off = 32; off > 0; off >>= 1) v += __shfl_down(v, off, 64);
        float vh[10];
#pragma unroll
        for (int m = 0; m < 10; ++m) {
            float ww = he[m];
#pragma unroll
            for (int off = 32; off > 0; off >>= 1) ww += __shfl_down(ww, off, 64);
            vh[m] = ww;
        }
        if ((threadIdx.x & 63) == 0) {
            atomAddF(&graph_acc[gid0 * 11 + 0], v);
#pragma unroll
            for (int m = 0; m < 10; ++m) atomAddF(&graph_acc[gid0 * 11 + 1 + m], vh[m]);
        }
    } else if (valid) {
        atomAddF(&graph_acc[gid * 11 + 0], n);
#pragma unroll
        for (int m = 0; m < 10; ++m) atomAddF(&graph_acc[gid * 11 + 1 + m], he[m]);
    }
}

// ---------------- launch ----------------

extern "C" void kernel_launch(void* const* d_in, const int* in_sizes, int n_in,
                              void* d_out, int out_size, void* d_ws, size_t ws_size,
                              hipStream_t stream) {
    const float* nodes     = (const float*)d_in[0];
    const float* edges     = (const float*)d_in[1];
    const int*   senders   = (const int*)d_in[2];
    const int*   receivers = (const int*)d_in[3];
    const int*   graph_ids = (const int*)d_in[4];
    const float* pn_w1 = (const float*)d_in[6];
    const float* pn_b1 = (const float*)d_in[7];
    const float* pn_w2 = (const float*)d_in[8];
    const float* pn_b2 = (const float*)d_in[9];
    const float* ue_w1 = (const float*)d_in[10];
    const float* ue_b1 = (const float*)d_in[11];
    const float* ue_w2 = (const float*)d_in[12];
    const float* ue_b2 = (const float*)d_in[13];
    const float* pe_w1 = (const float*)d_in[14];
    const float* pe_b1 = (const float*)d_in[15];
    const float* pe_w2 = (const float*)d_in[16];
    const float* pe_b2 = (const float*)d_in[17];
    const float* un_w1 = (const float*)d_in[18];
    const float* un_b1 = (const float*)d_in[19];
    const float* un_w2 = (const float*)d_in[20];
    const float* un_b2 = (const float*)d_in[21];
    const float* pr_w1 = (const float*)d_in[22];
    const float* pr_b1 = (const float*)d_in[23];
    const float* pr_w2 = (const float*)d_in[24];
    const float* pr_b2 = (const float*)d_in[25];

    float* ws        = (float*)d_ws;
    float* graph_acc = ws + GRAPH_ACC_OFF;
    float* partials  = ws + PARTIALS_OFF;
    float* fw        = ws + FW_OFF;
    float* outp      = (float*)d_out;

    if (ws_size >= (size_t)WS3_WORDS_NEEDED * 4) {
        // tier-1: split gather (2 blocks/bucket) + chunk-table lookup
        int* starts_T = (int*)ws + STARTS2_OFF;
        unsigned long long* pairs64 = (unsigned long long*)((int*)ws + PAIRS64_OFF);
        float* nodeacc2 = ws + NODEACC2_OFF;

        hipLaunchKernelGGL(k_part2, dim3(NPB2), dim3(P2_TPB), 0, stream,
                           ws, edges, senders, receivers, starts_T, pairs64,
                           pn_w1, pn_b1, pn_w2, pn_b2, ue_w1, ue_b1, ue_w2, ue_b2,
                           pe_w1, pe_b1, pe_w2, pe_b2, un_w1, un_b1, un_w2, un_b2);
        hipLaunchKernelGGL(k_gather2s, dim3(2 * NBKT), dim3(1024), 0, stream,
                           nodes, fw, starts_T, pairs64, nodeacc2);
        hipLaunchKernelGGL(k_nodes2, dim3(NBKT), dim3(1024), 0, stream,
                           nodes, graph_ids, fw, nodeacc2, graph_acc, partials);
        hipLaunchKernelGGL(k_final, dim3((N_GRAPHS_C + 255) / 256), dim3(256), 0, stream,
                           graph_acc, partials, pr_w1, pr_b1, pr_w2, pr_b2, outp);
    } else if (ws_size >= (size_t)WS2_WORDS_NEEDED * 4) {
        // tier-2: r3 champion (single-item gather, fused init)
        int* starts_T = (int*)ws + STARTS2_OFF;
        unsigned long long* pairs64 = (unsigned long long*)((int*)ws + PAIRS64_OFF);

        hipLaunchKernelGGL(k_part2, dim3(NPB2), dim3(P2_TPB), 0, stream,
                           ws, edges, senders, receivers, starts_T, pairs64,
                           pn_w1, pn_b1, pn_w2, pn_b2, ue_w1, ue_b1, ue_w2, ue_b2,
                           pe_w1, pe_b1, pe_w2, pe_b2, un_w1, un_b1, un_w2, un_b2);
        hipLaunchKernelGGL(k_gather2, dim3(NBKT), dim3(1024), 0, stream,
                           nodes, graph_ids, fw, starts_T, pairs64, graph_acc, partials);
        hipLaunchKernelGGL(k_final, dim3((N_GRAPHS_C + 255) / 256), dim3(256), 0, stream,
                           graph_acc, partials, pr_w1, pr_b1, pr_w2, pr_b2, outp);
    } else {
        float* node_acc = ws + OLD_NODE_ACC_OFF;
        int len4 = OLD_ZERO_WORDS / 4;
        hipLaunchKernelGGL(k_zero, dim3((len4 + 255) / 256), dim3(256), 0, stream, ws, len4);
        hipLaunchKernelGGL(k_fuse, dim3(1), dim3(64), 0, stream,
                           pn_w1, pn_b1, pn_w2, pn_b2, ue_w1, ue_b1, ue_w2, ue_b2,
                           pe_w1, pe_b1, pe_w2, pe_b2, un_w1, un_b1, un_w2, un_b2, fw);
        hipLaunchKernelGGL(k_edges, dim3((NGROUPS_C + 255) / 256), dim3(256), 0, stream,
                           nodes, edges, senders, receivers, fw, node_acc);
        hipLaunchKernelGGL(k_nodes, dim3((N_NODES_C + 255) / 256), dim3(256), 0, stream,
                           nodes, graph_ids, fw, node_acc, graph_acc);
        hipLaunchKernelGGL(k_final, dim3((N_GRAPHS_C + 255) / 256), dim3(256), 0, stream,
                           graph_acc, partials, pr_w1, pr_b1, pr_w2, pr_b2, outp);
    }
}